// Round 3
// baseline (265.500 us; speedup 1.0000x reference)
//
#include <hip/hip_runtime.h>
#include <cmath>

#define B_ 4
#define S_ 4096
#define D_ 1024
#define H_ 128
#define M_ (B_*S_)   // 16384 total rows

typedef _Float16 half8 __attribute__((ext_vector_type(8)));
typedef _Float16 half4 __attribute__((ext_vector_type(4)));
typedef float f32x4 __attribute__((ext_vector_type(4)));
typedef int i32x4 __attribute__((ext_vector_type(4)));

#define LOG2E 1.44269504088896340f

// ---------------------------------------------------------------------------
// Kernel 1: QKV projection.  out = x @ W^T + b  (fp32 in, fp16 out)
// grid = (M/64, 3): y=0 -> q (scaled by log2e/sqrt(H)), y=1 -> k, y=2 -> v^T
// Register-prefetch double buffering: global loads for kt+1 issued before
// the MFMA compute of kt so HBM/L3 latency hides under compute.
// ---------------------------------------------------------------------------
__global__ __launch_bounds__(256, 3) void proj_kernel(
    const float* __restrict__ x,
    const float* __restrict__ Wq, const float* __restrict__ bq,
    const float* __restrict__ Wk, const float* __restrict__ bk,
    const float* __restrict__ Wv, const float* __restrict__ bv,
    _Float16* __restrict__ qh, _Float16* __restrict__ kh,
    _Float16* __restrict__ vt)
{
    __shared__ _Float16 Xs[64][72];    // +8 pad: stride 144B, conflict-free
    __shared__ _Float16 Wsh[128][72];

    const int t = threadIdx.x;
    const int yb = blockIdx.y;
    const float* __restrict__ W    = (yb == 0) ? Wq : (yb == 1) ? Wk : Wv;
    const float* __restrict__ bias = (yb == 0) ? bq : (yb == 1) ? bk : bv;
    const int m0 = blockIdx.x * 64;
    const int w = t >> 6, lane = t & 63;
    const int lg = lane >> 4, lr = lane & 15;

    f32x4 acc[8];
    #pragma unroll
    for (int i = 0; i < 8; ++i) acc[i] = f32x4{0.f, 0.f, 0.f, 0.f};

    const int xrow = t >> 2, xc = (t & 3) * 16;   // X tile: 64x64, 16 f/thread
    const int wrow = t >> 1, wc2 = (t & 1) * 32;  // W tile: 128x64, 32 f/thread

    const float* xbase = x + (size_t)(m0 + xrow) * D_ + xc;
    const float* wbase = W + (size_t)wrow * D_ + wc2;

    float4 xf[4], wf[8];
    {   // prologue: load kt=0
        const float4* xs = (const float4*)xbase;
        #pragma unroll
        for (int i = 0; i < 4; ++i) xf[i] = xs[i];
        const float4* ws = (const float4*)wbase;
        #pragma unroll
        for (int i = 0; i < 8; ++i) wf[i] = ws[i];
    }

    for (int kt = 0; kt < 16; ++kt) {
        // staged regs -> LDS (fp32 -> fp16)
        #pragma unroll
        for (int i = 0; i < 4; ++i) {
            half4 h = { (_Float16)xf[i].x, (_Float16)xf[i].y,
                        (_Float16)xf[i].z, (_Float16)xf[i].w };
            *(half4*)&Xs[xrow][xc + 4 * i] = h;
        }
        #pragma unroll
        for (int i = 0; i < 8; ++i) {
            half4 h = { (_Float16)wf[i].x, (_Float16)wf[i].y,
                        (_Float16)wf[i].z, (_Float16)wf[i].w };
            *(half4*)&Wsh[wrow][wc2 + 4 * i] = h;
        }
        __syncthreads();
        if (kt < 15) {   // prefetch kt+1 (flies during MFMA below)
            const int k0 = (kt + 1) * 64;
            const float4* xs = (const float4*)(xbase + k0);
            #pragma unroll
            for (int i = 0; i < 4; ++i) xf[i] = xs[i];
            const float4* ws = (const float4*)(wbase + k0);
            #pragma unroll
            for (int i = 0; i < 8; ++i) wf[i] = ws[i];
        }
        #pragma unroll
        for (int kk = 0; kk < 2; ++kk) {
            half8 a = *(const half8*)&Xs[w * 16 + lr][kk * 32 + 8 * lg];
            #pragma unroll
            for (int ni = 0; ni < 8; ++ni) {
                half8 bfr = *(const half8*)&Wsh[ni * 16 + lr][kk * 32 + 8 * lg];
                acc[ni] = __builtin_amdgcn_mfma_f32_16x16x32_f16(a, bfr, acc[ni], 0, 0, 0);
            }
        }
        __syncthreads();
    }

    // q scale folds 1/sqrt(128) AND log2(e) (softmax runs in exp2 domain)
    const float qscale = 0.08838834764831845f * LOG2E;
    const int rowb = m0 + w * 16 + lg * 4;   // C/D: row = 4*(lane>>4)+r, col = ni*16+lr
    #pragma unroll
    for (int ni = 0; ni < 8; ++ni) {
        const int col = ni * 16 + lr;
        const float bval = bias[col];
        if (yb == 0) {
            #pragma unroll
            for (int r = 0; r < 4; ++r)
                qh[(size_t)(rowb + r) * H_ + col] = (_Float16)((acc[ni][r] + bval) * qscale);
        } else if (yb == 1) {
            #pragma unroll
            for (int r = 0; r < 4; ++r)
                kh[(size_t)(rowb + r) * H_ + col] = (_Float16)(acc[ni][r] + bval);
        } else {
            const int bb = rowb >> 12, s0 = rowb & (S_ - 1);
            half4 h;
            #pragma unroll
            for (int r = 0; r < 4; ++r) h[r] = (_Float16)(acc[ni][r] + bval);
            *(half4*)&vt[(size_t)bb * H_ * S_ + (size_t)col * S_ + s0] = h;
        }
    }
}

// ---------------------------------------------------------------------------
// Kernel 2: flash attention, KV-split. SWAPPED operand scheme:
//   S^T = mfma(K, Q)  -> lane owns one q-row (q = lane&15): softmax lane-local
//   O^T = mfma(V^T, P)-> acc rescale factor is lane-local too
// exp2-domain softmax (log2e folded into q), defer-max THR=8, XOR-swizzled
// K/V LDS, register-prefetch of next K/V tile, P exchange via cvt_pkrtz +
// ds_bpermute (no P LDS buffer).
// ---------------------------------------------------------------------------
__global__ __launch_bounds__(256, 3) void attn_kernel(
    const _Float16* __restrict__ qh, const _Float16* __restrict__ kh,
    const _Float16* __restrict__ vt, const int* __restrict__ mask,
    float* __restrict__ pout, float* __restrict__ pm, float* __restrict__ pl,
    const int nsplit)
{
    __shared__ _Float16 Ks[64][128];   // [kv][d], 16B-block XOR swizzle
    __shared__ _Float16 Vs[128][64];   // [h][kv], 16B-block XOR swizzle

    const int t = threadIdx.x;
    const int nblocks = 256 * nsplit;
    const int chunk = nblocks >> 3;
    const int id = blockIdx.x;
    const int swz = (id & 7) * chunk + (id >> 3);   // XCD-bijective swizzle
    const int qt   = swz & 63;
    const int rest = swz >> 6;
    const int sp = rest % nsplit;
    const int b  = rest / nsplit;
    const int q0 = qt * 64;
    const int w = t >> 6, lane = t & 63;
    const int lg = lane >> 4, lr = lane & 15;
    const int kvlen  = S_ / nsplit;
    const int iters  = kvlen >> 6;
    const int kvbase = sp * kvlen;

    // Q fragments (B-operand of QK^T): Q[q = w*16+lr][d = kk*32 + 8*lg + j]
    half8 qf[4];
    {
        const _Float16* qp = qh + (size_t)(b * S_ + q0 + w * 16 + lr) * H_ + 8 * lg;
        #pragma unroll
        for (int kk = 0; kk < 4; ++kk) qf[kk] = *(const half8*)(qp + kk * 32);
    }

    float m_ = -1e30f, l_ = 0.f;
    f32x4 acc[8];   // O^T: acc[ni][r] = O[q=lr][h = 16*ni + 4*lg + r]
    #pragma unroll
    for (int i = 0; i < 8; ++i) acc[i] = f32x4{0.f, 0.f, 0.f, 0.f};

    const int krow = t >> 2, kblk0 = (t & 3) * 4;   // K stage: 4x16B blocks
    const int vrow = t >> 1, vblk0 = (t & 1) * 4;   // V stage: 4x16B blocks
    const bool hi = (lg >= 2);
    const int idx0 = (16 * ((2 * lg + 0) & 3) + lr) * 4;  // bpermute src (bytes)
    const int idx1 = (16 * ((2 * lg + 1) & 3) + lr) * 4;

    const _Float16* kptr = kh + (size_t)(b * S_ + kvbase + krow) * H_ + kblk0 * 8;
    const _Float16* vptr = vt + (size_t)b * H_ * S_ + (size_t)vrow * S_ + kvbase + vblk0 * 8;
    const int*      mptr = mask + b * S_ + kvbase + lane;

    uint4 kr[4], vr[4];
    int mreg;
    {   // prologue: load tile 0
        const uint4* ks = (const uint4*)kptr;
        const uint4* vs = (const uint4*)vptr;
        #pragma unroll
        for (int i = 0; i < 4; ++i) kr[i] = ks[i];
        #pragma unroll
        for (int i = 0; i < 4; ++i) vr[i] = vs[i];
        mreg = *mptr;
    }

    for (int it = 0; it < iters; ++it) {
        const unsigned long long bz = __ballot(mreg == 0);  // this tile's mask bits
        // staged regs -> LDS, XOR-swizzled (write & read use same XOR)
        #pragma unroll
        for (int i = 0; i < 4; ++i)
            *(uint4*)&Ks[krow][((kblk0 + i) ^ (krow & 7)) * 8] = kr[i];
        #pragma unroll
        for (int i = 0; i < 4; ++i)
            *(uint4*)&Vs[vrow][((vblk0 + i) ^ (vrow & 7)) * 8] = vr[i];
        __syncthreads();

        if (it + 1 < iters) {   // prefetch next tile (hides under compute)
            kptr += 64 * H_; vptr += 64; mptr += 64;
            const uint4* ks = (const uint4*)kptr;
            const uint4* vs = (const uint4*)vptr;
            #pragma unroll
            for (int i = 0; i < 4; ++i) kr[i] = ks[i];
            #pragma unroll
            for (int i = 0; i < 4; ++i) vr[i] = vs[i];
            mreg = *mptr;
        }

        // S^T = K Q^T : sf[ni][r] = S'[q=lr][kv = 16*ni + 4*lg + r]
        f32x4 sf[4];
        #pragma unroll
        for (int i = 0; i < 4; ++i) sf[i] = f32x4{0.f, 0.f, 0.f, 0.f};
        #pragma unroll
        for (int kk = 0; kk < 4; ++kk) {
            #pragma unroll
            for (int ni = 0; ni < 4; ++ni) {
                half8 kb = *(const half8*)&Ks[ni * 16 + lr][((4 * kk + lg) ^ (lr & 7)) * 8];
                sf[ni] = __builtin_amdgcn_mfma_f32_16x16x32_f16(kb, qf[kk], sf[ni], 0, 0, 0);
            }
        }
        // padding mask via ballot bits (free when mask is all ones)
        if (bz) {
            #pragma unroll
            for (int ni = 0; ni < 4; ++ni) {
                #pragma unroll
                for (int r = 0; r < 4; ++r)
                    if ((bz >> (16 * ni + 4 * lg + r)) & 1ull) sf[ni][r] = -3e9f;
            }
        }
        // online softmax in exp2 domain (all lane-local except 2 shuffles)
        float tmax = fmaxf(fmaxf(fmaxf(sf[0][0], sf[0][1]), fmaxf(sf[0][2], sf[0][3])),
                           fmaxf(fmaxf(sf[1][0], sf[1][1]), fmaxf(sf[1][2], sf[1][3])));
        tmax = fmaxf(tmax,
               fmaxf(fmaxf(fmaxf(sf[2][0], sf[2][1]), fmaxf(sf[2][2], sf[2][3])),
                     fmaxf(fmaxf(sf[3][0], sf[3][1]), fmaxf(sf[3][2], sf[3][3]))));
        tmax = fmaxf(tmax, __shfl_xor(tmax, 16));
        tmax = fmaxf(tmax, __shfl_xor(tmax, 32));
        if (!__all(tmax <= m_ + 8.f)) {   // defer-max: skip rescale when safe
            const float mn  = fmaxf(m_, tmax);
            const float scl = exp2f(m_ - mn);
            m_ = mn; l_ *= scl;
            #pragma unroll
            for (int ni = 0; ni < 8; ++ni) acc[ni] *= scl;
        }
        float rsum = 0.f;
        #pragma unroll
        for (int ni = 0; ni < 4; ++ni) {
            #pragma unroll
            for (int r = 0; r < 4; ++r) {
                const float p = exp2f(sf[ni][r] - m_);
                sf[ni][r] = p;
                rsum += p;
            }
        }
        rsum += __shfl_xor(rsum, 16);
        rsum += __shfl_xor(rsum, 32);
        l_ += rsum;

        // pack P to fp16 pairs: pk[ni][rp] = (kv=16ni+4lg+2rp, +1) of q=lr
        int pk[4][2];
        #pragma unroll
        for (int ni = 0; ni < 4; ++ni) {
            #pragma unroll
            for (int rp = 0; rp < 2; ++rp) {
                auto h2 = __builtin_amdgcn_cvt_pkrtz(sf[ni][2 * rp], sf[ni][2 * rp + 1]);
                pk[ni][rp] = __builtin_bit_cast(int, h2);
            }
        }
        // exchange to PV B-fragment layout: lane needs P[q=lr][kv=32kk+8lg+j]
        i32x4 pbi[2];
        #pragma unroll
        for (int kk = 0; kk < 2; ++kk) {
            #pragma unroll
            for (int dd = 0; dd < 4; ++dd) {
                const int sidx = (dd >> 1) ? idx1 : idx0;
                const int a  = __builtin_amdgcn_ds_bpermute(sidx, pk[2 * kk][dd & 1]);
                const int bb = __builtin_amdgcn_ds_bpermute(sidx, pk[2 * kk + 1][dd & 1]);
                pbi[kk][dd] = hi ? bb : a;
            }
        }
        // O^T += V^T P^T
        #pragma unroll
        for (int kk = 0; kk < 2; ++kk) {
            const half8 pb = __builtin_bit_cast(half8, pbi[kk]);
            #pragma unroll
            for (int ni = 0; ni < 8; ++ni) {
                half8 vb = *(const half8*)&Vs[ni * 16 + lr][((4 * kk + lg) ^ (lr & 7)) * 8];
                acc[ni] = __builtin_amdgcn_mfma_f32_16x16x32_f16(vb, pb, acc[ni], 0, 0, 0);
            }
        }
        __syncthreads();
    }

    // store unnormalized partials: acc[ni] = 4 consecutive h at 16ni+4lg
    const int qrow = b * S_ + q0 + w * 16 + lr;
    float* op = pout + (size_t)(sp * M_ + qrow) * H_ + 4 * lg;
    #pragma unroll
    for (int ni = 0; ni < 8; ++ni)
        *(f32x4*)(op + 16 * ni) = acc[ni];
    if (lg == 0) {
        pm[sp * M_ + qrow] = m_;
        pl[sp * M_ + qrow] = l_;
    }
}

// ---------------------------------------------------------------------------
// Kernel 3: combine KV-split partials and normalize (exp2 domain).
// ---------------------------------------------------------------------------
__global__ __launch_bounds__(256) void combine_kernel(
    const float* __restrict__ pout, const float* __restrict__ pm,
    const float* __restrict__ pl, float* __restrict__ out, const int nsplit)
{
    const int idx = blockIdx.x * 256 + threadIdx.x;
    const int row = idx >> 7;          // global row
    const int h   = idx & (H_ - 1);
    float M = -1e30f;
    for (int sp = 0; sp < nsplit; ++sp) M = fmaxf(M, pm[sp * M_ + row]);
    float Z = 0.f, o = 0.f;
    for (int sp = 0; sp < nsplit; ++sp) {
        const float wgt = exp2f(pm[sp * M_ + row] - M);
        Z += wgt * pl[sp * M_ + row];
        o += wgt * pout[(size_t)(sp * M_ + row) * H_ + h];
    }
    out[idx] = o / Z;
}

// ---------------------------------------------------------------------------
extern "C" void kernel_launch(void* const* d_in, const int* in_sizes, int n_in,
                              void* d_out, int out_size, void* d_ws, size_t ws_size,
                              hipStream_t stream)
{
    (void)in_sizes; (void)n_in; (void)out_size;
    // setup_inputs order: inputs, Wk, bk, Wq, bq, Wv, bv, padding_mask
    const float* x  = (const float*)d_in[0];
    const float* Wk = (const float*)d_in[1];
    const float* bk = (const float*)d_in[2];
    const float* Wq = (const float*)d_in[3];
    const float* bq = (const float*)d_in[4];
    const float* Wv = (const float*)d_in[5];
    const float* bv = (const float*)d_in[6];
    const int* mask = (const int*)d_in[7];

    char* ws = (char*)d_ws;
    const size_t qkvBytes = (size_t)M_ * H_ * sizeof(_Float16);   // 4 MB each
    _Float16* qh = (_Float16*)ws;
    _Float16* kh = (_Float16*)(ws + qkvBytes);
    _Float16* vt = (_Float16*)(ws + 2 * qkvBytes);                // [B][H][S]
    char* rest = ws + 3 * qkvBytes;

    int nsplit = 4;
    const size_t perSplit = (size_t)M_ * H_ * 4 + 2 * (size_t)M_ * 4;
    while (nsplit > 1 && 3 * qkvBytes + (size_t)nsplit * perSplit > ws_size) nsplit >>= 1;

    float* pout = (float*)rest;
    float* pm   = (float*)(rest + (size_t)nsplit * M_ * H_ * 4);
    float* pl   = pm + (size_t)nsplit * M_;

    proj_kernel<<<dim3(M_ / 64, 3), 256, 0, stream>>>(x, Wq, bq, Wk, bk, Wv, bv, qh, kh, vt);
    attn_kernel<<<dim3(256 * nsplit), 256, 0, stream>>>(qh, kh, vt, mask, pout, pm, pl, nsplit);
    combine_kernel<<<dim3(M_ * H_ / 256), 256, 0, stream>>>(pout, pm, pl, (float*)d_out, nsplit);
}

// Round 5
// 157.971 us; speedup vs baseline: 1.6807x; 1.6807x over previous
//
#include <hip/hip_runtime.h>
#include <cmath>

#define B_ 4
#define S_ 4096
#define D_ 1024
#define H_ 128
#define M_ (B_*S_)   // 16384 total rows

typedef _Float16 half8 __attribute__((ext_vector_type(8)));
typedef _Float16 half4 __attribute__((ext_vector_type(4)));
typedef float f32x4 __attribute__((ext_vector_type(4)));
typedef int i32x4 __attribute__((ext_vector_type(4)));

#define LOG2E 1.44269504088896340f

// async global->LDS, 16B per lane; LDS dest is wave-uniform base + lane*16
__device__ __forceinline__ void gload16(const void* g, void* l) {
    __builtin_amdgcn_global_load_lds(
        (const __attribute__((address_space(1))) unsigned int*)g,
        (__attribute__((address_space(3))) unsigned int*)l,
        16, 0, 0);
}

// ---------------------------------------------------------------------------
// Kernel 1: QKV projection.  out = x @ W^T + b  (fp32 in, fp16 out)
// grid = (M/64, 3): y=0 -> q (scaled by log2e/sqrt(H)), y=1 -> k, y=2 -> v^T
// ---------------------------------------------------------------------------
__global__ __launch_bounds__(256, 3) void proj_kernel(
    const float* __restrict__ x,
    const float* __restrict__ Wq, const float* __restrict__ bq,
    const float* __restrict__ Wk, const float* __restrict__ bk,
    const float* __restrict__ Wv, const float* __restrict__ bv,
    _Float16* __restrict__ qh, _Float16* __restrict__ kh,
    _Float16* __restrict__ vt)
{
    __shared__ _Float16 Xs[64][72];    // +8 pad: stride 144B, conflict-free
    __shared__ _Float16 Wsh[128][72];

    const int t = threadIdx.x;
    const int yb = blockIdx.y;
    const float* __restrict__ W    = (yb == 0) ? Wq : (yb == 1) ? Wk : Wv;
    const float* __restrict__ bias = (yb == 0) ? bq : (yb == 1) ? bk : bv;
    const int m0 = blockIdx.x * 64;
    const int w = t >> 6, lane = t & 63;
    const int lg = lane >> 4, lr = lane & 15;

    f32x4 acc[8];
    #pragma unroll
    for (int i = 0; i < 8; ++i) acc[i] = f32x4{0.f, 0.f, 0.f, 0.f};

    const int xrow = t >> 2, xc = (t & 3) * 16;   // X tile: 64x64, 16 f/thread
    const int wrow = t >> 1, wc2 = (t & 1) * 32;  // W tile: 128x64, 32 f/thread

    const float* xbase = x + (size_t)(m0 + xrow) * D_ + xc;
    const float* wbase = W + (size_t)wrow * D_ + wc2;

    float4 xf[4], wf[8];
    {   // prologue: load kt=0
        const float4* xs = (const float4*)xbase;
        #pragma unroll
        for (int i = 0; i < 4; ++i) xf[i] = xs[i];
        const float4* ws = (const float4*)wbase;
        #pragma unroll
        for (int i = 0; i < 8; ++i) wf[i] = ws[i];
    }

    for (int kt = 0; kt < 16; ++kt) {
        #pragma unroll
        for (int i = 0; i < 4; ++i) {
            half4 h = { (_Float16)xf[i].x, (_Float16)xf[i].y,
                        (_Float16)xf[i].z, (_Float16)xf[i].w };
            *(half4*)&Xs[xrow][xc + 4 * i] = h;
        }
        #pragma unroll
        for (int i = 0; i < 8; ++i) {
            half4 h = { (_Float16)wf[i].x, (_Float16)wf[i].y,
                        (_Float16)wf[i].z, (_Float16)wf[i].w };
            *(half4*)&Wsh[wrow][wc2 + 4 * i] = h;
        }
        __syncthreads();
        if (kt < 15) {   // prefetch kt+1 (flies during MFMA below)
            const int k0 = (kt + 1) * 64;
            const float4* xs = (const float4*)(xbase + k0);
            #pragma unroll
            for (int i = 0; i < 4; ++i) xf[i] = xs[i];
            const float4* ws = (const float4*)(wbase + k0);
            #pragma unroll
            for (int i = 0; i < 8; ++i) wf[i] = ws[i];
        }
        #pragma unroll
        for (int kk = 0; kk < 2; ++kk) {
            half8 a = *(const half8*)&Xs[w * 16 + lr][kk * 32 + 8 * lg];
            #pragma unroll
            for (int ni = 0; ni < 8; ++ni) {
                half8 bfr = *(const half8*)&Wsh[ni * 16 + lr][kk * 32 + 8 * lg];
                acc[ni] = __builtin_amdgcn_mfma_f32_16x16x32_f16(a, bfr, acc[ni], 0, 0, 0);
            }
        }
        __syncthreads();
    }

    // q scale folds 1/sqrt(128) AND log2(e) (softmax runs in exp2 domain)
    const float qscale = 0.08838834764831845f * LOG2E;
    const int rowb = m0 + w * 16 + lg * 4;   // C/D: row = 4*(lane>>4)+r, col = ni*16+lr
    #pragma unroll
    for (int ni = 0; ni < 8; ++ni) {
        const int col = ni * 16 + lr;
        const float bval = bias[col];
        if (yb == 0) {
            #pragma unroll
            for (int r = 0; r < 4; ++r)
                qh[(size_t)(rowb + r) * H_ + col] = (_Float16)((acc[ni][r] + bval) * qscale);
        } else if (yb == 1) {
            #pragma unroll
            for (int r = 0; r < 4; ++r)
                kh[(size_t)(rowb + r) * H_ + col] = (_Float16)(acc[ni][r] + bval);
        } else {
            const int bb = rowb >> 12, s0 = rowb & (S_ - 1);
            half4 h;
            #pragma unroll
            for (int r = 0; r < 4; ++r) h[r] = (_Float16)(acc[ni][r] + bval);
            *(half4*)&vt[(size_t)bb * H_ * S_ + (size_t)col * S_ + s0] = h;
        }
    }
}

// ---------------------------------------------------------------------------
// Kernel 2: flash attention, KV-split. Swapped-operand MFMA (lane-local
// softmax), exp2 domain, defer-max, K/V staged via global_load_lds with
// pre-swizzled GLOBAL source + linear LDS dest (content swizzle identical
// to the R3-passing layout), single buffer, m97-style 2-barrier loop with
// real __syncthreads (compiler-managed drains -> race-free by construction).
// ---------------------------------------------------------------------------
__global__ __launch_bounds__(256, 3) void attn_kernel(
    const _Float16* __restrict__ qh, const _Float16* __restrict__ kh,
    const _Float16* __restrict__ vt, const int* __restrict__ mask,
    float* __restrict__ pout, float* __restrict__ pm, float* __restrict__ pl,
    const int nsplit)
{
    __shared__ _Float16 Ks[64][128];   // [kv][d]; content at (row,blk)=G[row][blk^(row&7)]
    __shared__ _Float16 Vs[128][64];   // [h][kv]; same relation

    const int t = threadIdx.x;
    const int nblocks = 256 * nsplit;
    const int chunk = nblocks >> 3;
    const int id = blockIdx.x;
    const int swz = (id & 7) * chunk + (id >> 3);   // XCD-bijective swizzle
    const int qt   = swz & 63;
    const int rest = swz >> 6;
    const int sp = rest % nsplit;
    const int b  = rest / nsplit;
    const int q0 = qt * 64;
    const int w = t >> 6, lane = t & 63;
    const int lg = lane >> 4, lr = lane & 15;
    const int kvlen  = S_ / nsplit;
    const int iters  = kvlen >> 6;
    const int kvbase = sp * kvlen;

    // per-lane byte offsets of the SWIZZLED global source (loop-invariant).
    // gload16 writes LDS linearly (base + lane*16B), so the source address
    // carries the XOR permutation instead (rule: both-sides-or-neither).
    int kbyte[4], vbyte[4];
    #pragma unroll
    for (int i = 0; i < 4; ++i) {
        const int krow = 16 * w + 4 * i + (lane >> 4);
        const int kblk = (lane & 15) ^ (krow & 7);
        kbyte[i] = (krow * H_ + kblk * 8) * 2;
        const int vrow = 32 * w + 8 * i + (lane >> 3);
        const int vblk = (lane & 7) ^ (lane >> 3);   // vrow&7 == lane>>3
        vbyte[i] = (vrow * S_ + vblk * 8) * 2;
    }
    const char* kbase_b = (const char*)(kh + (size_t)(b * S_ + kvbase) * H_);
    const char* vbase_b = (const char*)(vt + (size_t)b * H_ * S_ + kvbase);
    const char* mbase_b = (const char*)(mask + b * S_ + kvbase + lane);

    // Q fragments (B-operand of QK^T): Q[q = w*16+lr][d = kk*32 + 8*lg + j]
    half8 qf[4];
    {
        const _Float16* qp = qh + (size_t)(b * S_ + q0 + w * 16 + lr) * H_ + 8 * lg;
        #pragma unroll
        for (int kk = 0; kk < 4; ++kk) qf[kk] = *(const half8*)(qp + kk * 32);
    }

    float m_ = -1e30f, l_ = 0.f;
    f32x4 acc[8];   // O^T: acc[ni][r] = O[q = w*16+lr][h = 16*ni + 4*lg + r]
    #pragma unroll
    for (int i = 0; i < 8; ++i) acc[i] = f32x4{0.f, 0.f, 0.f, 0.f};

    const bool hi = (lg >= 2);
    const int idx0 = (16 * ((2 * lg + 0) & 3) + lr) * 4;  // bpermute src (bytes)
    const int idx1 = (16 * ((2 * lg + 1) & 3) + lr) * 4;

    for (int it = 0; it < iters; ++it) {
        if (it) __syncthreads();   // WAR: all waves done reading previous tile
        {
            const char* kb_t = kbase_b + (size_t)it * (64 * H_ * 2);
            const char* vb_t = vbase_b + (size_t)it * (64 * 2);
            #pragma unroll
            for (int i = 0; i < 4; ++i)
                gload16(kb_t + kbyte[i], &Ks[16 * w + 4 * i][0]);
            #pragma unroll
            for (int i = 0; i < 4; ++i)
                gload16(vb_t + vbyte[i], &Vs[32 * w + 8 * i][0]);
        }
        const int mreg = *(const int*)(mbase_b + (size_t)it * 256);
        __syncthreads();           // RAW: drains vmcnt -> LDS tile valid

        const unsigned long long bz = __ballot(mreg == 0);
        // S^T = K Q^T : sf[ni][r] = S'[q=lr(+16w)][kv = 16*ni + 4*lg + r]
        f32x4 sf[4];
        #pragma unroll
        for (int i = 0; i < 4; ++i) sf[i] = f32x4{0.f, 0.f, 0.f, 0.f};
        #pragma unroll
        for (int kk = 0; kk < 4; ++kk) {
            #pragma unroll
            for (int ni = 0; ni < 4; ++ni) {
                half8 kb = *(const half8*)&Ks[ni * 16 + lr][((4 * kk + lg) ^ (lr & 7)) * 8];
                sf[ni] = __builtin_amdgcn_mfma_f32_16x16x32_f16(kb, qf[kk], sf[ni], 0, 0, 0);
            }
        }
        if (bz) {   // padding mask (reference: where(mask==0, -1e9))
            #pragma unroll
            for (int ni = 0; ni < 4; ++ni) {
                #pragma unroll
                for (int r = 0; r < 4; ++r)
                    if ((bz >> (16 * ni + 4 * lg + r)) & 1ull) sf[ni][r] = -3e9f;
            }
        }
        // online softmax in exp2 domain (lane-local except 2 shuffles)
        float tmax = fmaxf(fmaxf(fmaxf(sf[0][0], sf[0][1]), fmaxf(sf[0][2], sf[0][3])),
                           fmaxf(fmaxf(sf[1][0], sf[1][1]), fmaxf(sf[1][2], sf[1][3])));
        tmax = fmaxf(tmax,
               fmaxf(fmaxf(fmaxf(sf[2][0], sf[2][1]), fmaxf(sf[2][2], sf[2][3])),
                     fmaxf(fmaxf(sf[3][0], sf[3][1]), fmaxf(sf[3][2], sf[3][3]))));
        tmax = fmaxf(tmax, __shfl_xor(tmax, 16));
        tmax = fmaxf(tmax, __shfl_xor(tmax, 32));
        if (!__all(tmax <= m_ + 8.f)) {   // defer-max: skip rescale when safe
            const float mn  = fmaxf(m_, tmax);
            const float scl = exp2f(m_ - mn);
            m_ = mn; l_ *= scl;
            #pragma unroll
            for (int ni = 0; ni < 8; ++ni) acc[ni] *= scl;
        }
        float rsum = 0.f;
        #pragma unroll
        for (int ni = 0; ni < 4; ++ni) {
            #pragma unroll
            for (int r = 0; r < 4; ++r) {
                const float p = exp2f(sf[ni][r] - m_);
                sf[ni][r] = p;
                rsum += p;
            }
        }
        rsum += __shfl_xor(rsum, 16);
        rsum += __shfl_xor(rsum, 32);
        l_ += rsum;

        // pack P to fp16 pairs, exchange to PV B-fragment layout via bpermute
        int pk[4][2];
        #pragma unroll
        for (int ni = 0; ni < 4; ++ni) {
            #pragma unroll
            for (int rp = 0; rp < 2; ++rp) {
                auto h2 = __builtin_amdgcn_cvt_pkrtz(sf[ni][2 * rp], sf[ni][2 * rp + 1]);
                pk[ni][rp] = __builtin_bit_cast(int, h2);
            }
        }
        i32x4 pbi[2];
        #pragma unroll
        for (int kk = 0; kk < 2; ++kk) {
            #pragma unroll
            for (int dd = 0; dd < 4; ++dd) {
                const int sidx = (dd >> 1) ? idx1 : idx0;
                const int a  = __builtin_amdgcn_ds_bpermute(sidx, pk[2 * kk][dd & 1]);
                const int bb = __builtin_amdgcn_ds_bpermute(sidx, pk[2 * kk + 1][dd & 1]);
                pbi[kk][dd] = hi ? bb : a;
            }
        }
        // O^T += V^T P^T
        #pragma unroll
        for (int kk = 0; kk < 2; ++kk) {
            const half8 pb = __builtin_bit_cast(half8, pbi[kk]);
            #pragma unroll
            for (int ni = 0; ni < 8; ++ni) {
                half8 vb = *(const half8*)&Vs[ni * 16 + lr][((4 * kk + lg) ^ (lr & 7)) * 8];
                acc[ni] = __builtin_amdgcn_mfma_f32_16x16x32_f16(vb, pb, acc[ni], 0, 0, 0);
            }
        }
    }

    // store unnormalized partials (R3-proven epilogue)
    const int qrow = b * S_ + q0 + w * 16 + lr;
    float* op = pout + (size_t)(sp * M_ + qrow) * H_ + 4 * lg;
    #pragma unroll
    for (int ni = 0; ni < 8; ++ni)
        *(f32x4*)(op + 16 * ni) = acc[ni];
    if (lg == 0) {
        pm[sp * M_ + qrow] = m_;
        pl[sp * M_ + qrow] = l_;
    }
}

// ---------------------------------------------------------------------------
// Kernel 3: combine KV-split partials and normalize (exp2 domain).
// ---------------------------------------------------------------------------
__global__ __launch_bounds__(256) void combine_kernel(
    const float* __restrict__ pout, const float* __restrict__ pm,
    const float* __restrict__ pl, float* __restrict__ out, const int nsplit)
{
    const int idx = blockIdx.x * 256 + threadIdx.x;
    const int row = idx >> 7;          // global row
    const int h   = idx & (H_ - 1);
    float M = -1e30f;
    for (int sp = 0; sp < nsplit; ++sp) M = fmaxf(M, pm[sp * M_ + row]);
    float Z = 0.f, o = 0.f;
    for (int sp = 0; sp < nsplit; ++sp) {
        const float wgt = exp2f(pm[sp * M_ + row] - M);
        Z += wgt * pl[sp * M_ + row];
        o += wgt * pout[(size_t)(sp * M_ + row) * H_ + h];
    }
    out[idx] = o / Z;
}

// ---------------------------------------------------------------------------
extern "C" void kernel_launch(void* const* d_in, const int* in_sizes, int n_in,
                              void* d_out, int out_size, void* d_ws, size_t ws_size,
                              hipStream_t stream)
{
    (void)in_sizes; (void)n_in; (void)out_size;
    // setup_inputs order: inputs, Wk, bk, Wq, bq, Wv, bv, padding_mask
    const float* x  = (const float*)d_in[0];
    const float* Wk = (const float*)d_in[1];
    const float* bk = (const float*)d_in[2];
    const float* Wq = (const float*)d_in[3];
    const float* bq = (const float*)d_in[4];
    const float* Wv = (const float*)d_in[5];
    const float* bv = (const float*)d_in[6];
    const int* mask = (const int*)d_in[7];

    char* ws = (char*)d_ws;
    const size_t qkvBytes = (size_t)M_ * H_ * sizeof(_Float16);   // 4 MB each
    _Float16* qh = (_Float16*)ws;
    _Float16* kh = (_Float16*)(ws + qkvBytes);
    _Float16* vt = (_Float16*)(ws + 2 * qkvBytes);                // [B][H][S]
    char* rest = ws + 3 * qkvBytes;

    int nsplit = 4;
    const size_t perSplit = (size_t)M_ * H_ * 4 + 2 * (size_t)M_ * 4;
    while (nsplit > 1 && 3 * qkvBytes + (size_t)nsplit * perSplit > ws_size) nsplit >>= 1;

    float* pout = (float*)rest;
    float* pm   = (float*)(rest + (size_t)nsplit * M_ * H_ * 4);
    float* pl   = pm + (size_t)nsplit * M_;

    proj_kernel<<<dim3(M_ / 64, 3), 256, 0, stream>>>(x, Wq, bq, Wk, bk, Wv, bv, qh, kh, vt);
    attn_kernel<<<dim3(256 * nsplit), 256, 0, stream>>>(qh, kh, vt, mask, pout, pm, pl, nsplit);
    combine_kernel<<<dim3(M_ * H_ / 256), 256, 0, stream>>>(pout, pm, pl, (float*)d_out, nsplit);
}

// Round 6
// 152.020 us; speedup vs baseline: 1.7465x; 1.0391x over previous
//
#include <hip/hip_runtime.h>
#include <cmath>

#define B_ 4
#define S_ 4096
#define D_ 1024
#define H_ 128
#define M_ (B_*S_)   // 16384 total rows

typedef _Float16 half8 __attribute__((ext_vector_type(8)));
typedef _Float16 half4 __attribute__((ext_vector_type(4)));
typedef float f32x4 __attribute__((ext_vector_type(4)));
typedef int i32x4 __attribute__((ext_vector_type(4)));

#define LOG2E 1.44269504088896340f

// async global->LDS, 16B per lane; LDS dest is wave-uniform base + lane*16
__device__ __forceinline__ void gload16(const void* g, void* l) {
    __builtin_amdgcn_global_load_lds(
        (const __attribute__((address_space(1))) unsigned int*)g,
        (__attribute__((address_space(3))) unsigned int*)l,
        16, 0, 0);
}

// ---------------------------------------------------------------------------
// Kernel 1: QKV projection.  out = x @ W^T + b  (fp32 in, fp16 out)
// grid = (M/64, 3): y=0 -> q (scaled by log2e/sqrt(H)), y=1 -> k, y=2 -> v^T
// One __syncthreads per K-tile; double-buffered LDS; 2-deep register
// pipeline (named A/B sets, loop unrolled x2) so each load batch is in
// flight ~2 intervals (> HBM latency).
// ---------------------------------------------------------------------------
__global__ __launch_bounds__(256, 2) void proj_kernel(
    const float* __restrict__ x,
    const float* __restrict__ Wq, const float* __restrict__ bq,
    const float* __restrict__ Wk, const float* __restrict__ bk,
    const float* __restrict__ Wv, const float* __restrict__ bv,
    _Float16* __restrict__ qh, _Float16* __restrict__ kh,
    _Float16* __restrict__ vt)
{
    __shared__ _Float16 Xs[2][64][72];    // +8 pad: stride 144B
    __shared__ _Float16 Wsh[2][128][72];

    const int t = threadIdx.x;
    const int yb = blockIdx.y;
    const float* __restrict__ W    = (yb == 0) ? Wq : (yb == 1) ? Wk : Wv;
    const float* __restrict__ bias = (yb == 0) ? bq : (yb == 1) ? bk : bv;
    const int m0 = blockIdx.x * 64;
    const int w = t >> 6, lane = t & 63;
    const int lg = lane >> 4, lr = lane & 15;

    f32x4 acc[8];
    #pragma unroll
    for (int i = 0; i < 8; ++i) acc[i] = f32x4{0.f, 0.f, 0.f, 0.f};

    const int xrow = t >> 2, xc = (t & 3) * 16;   // X tile: 64x64, 16 f/thread
    const int wrow = t >> 1, wc2 = (t & 1) * 32;  // W tile: 128x64, 32 f/thread

    const float* xbase = x + (size_t)(m0 + xrow) * D_ + xc;
    const float* wbase = W + (size_t)wrow * D_ + wc2;

    float4 xfA[4], wfA[8], xfB[4], wfB[8];

#define PISSUE(KT, XS, WS)                                                    \
    {                                                                         \
        const float4* xs_ = (const float4*)(xbase + (KT) * 64);               \
        _Pragma("unroll") for (int i = 0; i < 4; ++i) XS[i] = xs_[i];         \
        const float4* ws_ = (const float4*)(wbase + (KT) * 64);               \
        _Pragma("unroll") for (int i = 0; i < 8; ++i) WS[i] = ws_[i];         \
    }
#define PWRITE(XS, WS, BUF)                                                   \
    {                                                                         \
        _Pragma("unroll") for (int i = 0; i < 4; ++i) {                       \
            half4 h = { (_Float16)XS[i].x, (_Float16)XS[i].y,                 \
                        (_Float16)XS[i].z, (_Float16)XS[i].w };               \
            *(half4*)&Xs[BUF][xrow][xc + 4 * i] = h;                          \
        }                                                                     \
        _Pragma("unroll") for (int i = 0; i < 8; ++i) {                       \
            half4 h = { (_Float16)WS[i].x, (_Float16)WS[i].y,                 \
                        (_Float16)WS[i].z, (_Float16)WS[i].w };               \
            *(half4*)&Wsh[BUF][wrow][wc2 + 4 * i] = h;                        \
        }                                                                     \
    }
#define PMFMA(BUF)                                                            \
    {                                                                         \
        _Pragma("unroll") for (int kk = 0; kk < 2; ++kk) {                    \
            half8 a = *(const half8*)&Xs[BUF][w * 16 + lr][kk * 32 + 8 * lg]; \
            _Pragma("unroll") for (int ni = 0; ni < 8; ++ni) {                \
                half8 bfr = *(const half8*)&Wsh[BUF][ni * 16 + lr][kk * 32 + 8 * lg]; \
                acc[ni] = __builtin_amdgcn_mfma_f32_16x16x32_f16(a, bfr, acc[ni], 0, 0, 0); \
            }                                                                 \
        }                                                                     \
    }

    PISSUE(0, xfA, wfA)
    PISSUE(1, xfB, wfB)
    PWRITE(xfA, wfA, 0)
    __syncthreads();

    for (int kt = 0; kt < 16; kt += 2) {
        // ---- even tile kt (buf 0) ----
        if (kt + 2 < 16) PISSUE(kt + 2, xfA, wfA)      // flight: ~2 intervals
        PMFMA(0)
        PWRITE(xfB, wfB, 1)                            // tile kt+1 -> buf 1
        __syncthreads();
        // ---- odd tile kt+1 (buf 1) ----
        if (kt + 3 < 16) PISSUE(kt + 3, xfB, wfB)
        PMFMA(1)
        if (kt + 2 < 16) PWRITE(xfA, wfA, 0)           // tile kt+2 -> buf 0
        __syncthreads();
    }
#undef PISSUE
#undef PWRITE
#undef PMFMA

    // q scale folds 1/sqrt(128) AND log2(e) (softmax runs in exp2 domain)
    const float qscale = 0.08838834764831845f * LOG2E;
    const int rowb = m0 + w * 16 + lg * 4;   // C/D: row = 4*(lane>>4)+r, col = ni*16+lr
    #pragma unroll
    for (int ni = 0; ni < 8; ++ni) {
        const int col = ni * 16 + lr;
        const float bval = bias[col];
        if (yb == 0) {
            #pragma unroll
            for (int r = 0; r < 4; ++r)
                qh[(size_t)(rowb + r) * H_ + col] = (_Float16)((acc[ni][r] + bval) * qscale);
        } else if (yb == 1) {
            #pragma unroll
            for (int r = 0; r < 4; ++r)
                kh[(size_t)(rowb + r) * H_ + col] = (_Float16)(acc[ni][r] + bval);
        } else {
            const int bb = rowb >> 12, s0 = rowb & (S_ - 1);
            half4 h;
            #pragma unroll
            for (int r = 0; r < 4; ++r) h[r] = (_Float16)(acc[ni][r] + bval);
            *(half4*)&vt[(size_t)bb * H_ * S_ + (size_t)col * S_ + s0] = h;
        }
    }
}

// ---------------------------------------------------------------------------
// Kernel 2: flash attention, KV-split. Swapped-operand MFMA (lane-local
// softmax), exp2 domain, defer-max, pre-swizzled-source gload16 staging.
// Ping-pong double-buffered K/V, ONE __syncthreads per tile: next tile's
// gloads are issued before compute so they fly the whole compute interval.
// ---------------------------------------------------------------------------
__device__ __forceinline__ void attn_tile(
    const _Float16 (&Kb)[64][128], const _Float16 (&Vb)[128][64],
    const half8 qf[4], f32x4 acc[8], float& m_, float& l_, int muse,
    int lg, int lr, bool hi, int idx0, int idx1)
{
    const unsigned long long bz = __ballot(muse == 0);
    // S^T = K Q^T : sf[ni][r] = S'[q-row][kv = 16*ni + 4*lg + r]
    f32x4 sf[4];
    #pragma unroll
    for (int i = 0; i < 4; ++i) sf[i] = f32x4{0.f, 0.f, 0.f, 0.f};
    #pragma unroll
    for (int kk = 0; kk < 4; ++kk) {
        #pragma unroll
        for (int ni = 0; ni < 4; ++ni) {
            half8 kb = *(const half8*)&Kb[ni * 16 + lr][((4 * kk + lg) ^ (lr & 7)) * 8];
            sf[ni] = __builtin_amdgcn_mfma_f32_16x16x32_f16(kb, qf[kk], sf[ni], 0, 0, 0);
        }
    }
    if (bz) {   // padding mask (reference: where(mask==0, -1e9))
        #pragma unroll
        for (int ni = 0; ni < 4; ++ni) {
            #pragma unroll
            for (int r = 0; r < 4; ++r)
                if ((bz >> (16 * ni + 4 * lg + r)) & 1ull) sf[ni][r] = -3e9f;
        }
    }
    // online softmax in exp2 domain (lane-local except 2 shuffles)
    float tmax = fmaxf(fmaxf(fmaxf(sf[0][0], sf[0][1]), fmaxf(sf[0][2], sf[0][3])),
                       fmaxf(fmaxf(sf[1][0], sf[1][1]), fmaxf(sf[1][2], sf[1][3])));
    tmax = fmaxf(tmax,
           fmaxf(fmaxf(fmaxf(sf[2][0], sf[2][1]), fmaxf(sf[2][2], sf[2][3])),
                 fmaxf(fmaxf(sf[3][0], sf[3][1]), fmaxf(sf[3][2], sf[3][3]))));
    tmax = fmaxf(tmax, __shfl_xor(tmax, 16));
    tmax = fmaxf(tmax, __shfl_xor(tmax, 32));
    if (!__all(tmax <= m_ + 8.f)) {   // defer-max: skip rescale when safe
        const float mn  = fmaxf(m_, tmax);
        const float scl = exp2f(m_ - mn);
        m_ = mn; l_ *= scl;
        #pragma unroll
        for (int ni = 0; ni < 8; ++ni) acc[ni] *= scl;
    }
    float rsum = 0.f;
    #pragma unroll
    for (int ni = 0; ni < 4; ++ni) {
        #pragma unroll
        for (int r = 0; r < 4; ++r) {
            const float p = exp2f(sf[ni][r] - m_);
            sf[ni][r] = p;
            rsum += p;
        }
    }
    rsum += __shfl_xor(rsum, 16);
    rsum += __shfl_xor(rsum, 32);
    l_ += rsum;

    // pack P to fp16 pairs, exchange to PV B-fragment layout via bpermute
    int pk[4][2];
    #pragma unroll
    for (int ni = 0; ni < 4; ++ni) {
        #pragma unroll
        for (int rp = 0; rp < 2; ++rp) {
            auto h2 = __builtin_amdgcn_cvt_pkrtz(sf[ni][2 * rp], sf[ni][2 * rp + 1]);
            pk[ni][rp] = __builtin_bit_cast(int, h2);
        }
    }
    i32x4 pbi[2];
    #pragma unroll
    for (int kk = 0; kk < 2; ++kk) {
        #pragma unroll
        for (int dd = 0; dd < 4; ++dd) {
            const int sidx = (dd >> 1) ? idx1 : idx0;
            const int a  = __builtin_amdgcn_ds_bpermute(sidx, pk[2 * kk][dd & 1]);
            const int bb = __builtin_amdgcn_ds_bpermute(sidx, pk[2 * kk + 1][dd & 1]);
            pbi[kk][dd] = hi ? bb : a;
        }
    }
    // O^T += V^T P^T
    #pragma unroll
    for (int kk = 0; kk < 2; ++kk) {
        const half8 pb = __builtin_bit_cast(half8, pbi[kk]);
        #pragma unroll
        for (int ni = 0; ni < 8; ++ni) {
            half8 vb = *(const half8*)&Vb[ni * 16 + lr][((4 * kk + lg) ^ (lr & 7)) * 8];
            acc[ni] = __builtin_amdgcn_mfma_f32_16x16x32_f16(vb, pb, acc[ni], 0, 0, 0);
        }
    }
}

__global__ __launch_bounds__(256, 2) void attn_kernel(
    const _Float16* __restrict__ qh, const _Float16* __restrict__ kh,
    const _Float16* __restrict__ vt, const int* __restrict__ mask,
    float* __restrict__ pout, float* __restrict__ pm, float* __restrict__ pl,
    const int nsplit)
{
    __shared__ _Float16 Ks[2][64][128];   // [buf][kv][d]; content swizzled
    __shared__ _Float16 Vs[2][128][64];   // [buf][h][kv]

    const int t = threadIdx.x;
    const int id = blockIdx.x;
    // L2-locality swizzle: each XCD owns ncombo/8 (b,split) combos so its
    // K/V working set (512 KB per combo) fits the 4 MB per-XCD L2.
    int qt, sp, b;
    const int ncombo = B_ * nsplit;
    if ((ncombo & 7) == 0) {
        const int per_xcd = ncombo >> 3;
        const int j = id >> 3;
        qt = j & 63;
        const int combo = (id & 7) * per_xcd + (j >> 6);
        sp = combo % nsplit; b = combo / nsplit;
    } else {
        qt = id & 63;
        const int rest = id >> 6;
        sp = rest % nsplit; b = rest / nsplit;
    }
    const int q0 = qt * 64;
    const int w = t >> 6, lane = t & 63;
    const int lg = lane >> 4, lr = lane & 15;
    const int kvlen  = S_ / nsplit;
    const int iters  = kvlen >> 6;
    const int kvbase = sp * kvlen;

    // per-lane byte offsets of the SWIZZLED global source (loop-invariant).
    // gload16 writes LDS linearly (base + lane*16B); the source address
    // carries the XOR permutation (both-sides-or-neither rule).
    int kbyte[4], vbyte[4];
    #pragma unroll
    for (int i = 0; i < 4; ++i) {
        const int krow = 16 * w + 4 * i + (lane >> 4);
        const int kblk = (lane & 15) ^ (krow & 7);
        kbyte[i] = (krow * H_ + kblk * 8) * 2;
        const int vrow = 32 * w + 8 * i + (lane >> 3);
        const int vblk = (lane & 7) ^ (lane >> 3);   // vrow&7 == lane>>3
        vbyte[i] = (vrow * S_ + vblk * 8) * 2;
    }
    const char* kbase_b = (const char*)(kh + (size_t)(b * S_ + kvbase) * H_);
    const char* vbase_b = (const char*)(vt + (size_t)b * H_ * S_ + kvbase);
    const char* mbase_b = (const char*)(mask + b * S_ + kvbase + lane);

#define ISSUE_TILE(IT, NB)                                                    \
    {                                                                         \
        const char* kb_t = kbase_b + (size_t)(IT) * (64 * H_ * 2);            \
        const char* vb_t = vbase_b + (size_t)(IT) * (64 * 2);                 \
        _Pragma("unroll")                                                     \
        for (int i = 0; i < 4; ++i)                                           \
            gload16(kb_t + kbyte[i], &Ks[NB][16 * w + 4 * i][0]);             \
        _Pragma("unroll")                                                     \
        for (int i = 0; i < 4; ++i)                                           \
            gload16(vb_t + vbyte[i], &Vs[NB][32 * w + 8 * i][0]);             \
    }

    // Q fragments (B-operand of QK^T): Q[q = w*16+lr][d = kk*32 + 8*lg + j]
    half8 qf[4];
    {
        const _Float16* qp = qh + (size_t)(b * S_ + q0 + w * 16 + lr) * H_ + 8 * lg;
        #pragma unroll
        for (int kk = 0; kk < 4; ++kk) qf[kk] = *(const half8*)(qp + kk * 32);
    }

    float m_ = -1e30f, l_ = 0.f;
    f32x4 acc[8];   // O^T: acc[ni][r] = O[q = w*16+lr][h = 16*ni + 4*lg + r]
    #pragma unroll
    for (int i = 0; i < 8; ++i) acc[i] = f32x4{0.f, 0.f, 0.f, 0.f};

    const bool hi = (lg >= 2);
    const int idx0 = (16 * ((2 * lg + 0) & 3) + lr) * 4;  // bpermute src (bytes)
    const int idx1 = (16 * ((2 * lg + 1) & 3) + lr) * 4;

    ISSUE_TILE(0, 0)
    int mA = *(const int*)mbase_b;
    int mB = 0;
    __syncthreads();   // tile 0 staged

    for (int it = 0; it < iters; it += 2) {
        // ---- tile it (buf 0); prefetch it+1 flies during this compute ----
        if (it + 1 < iters) {
            ISSUE_TILE(it + 1, 1)
            mB = *(const int*)(mbase_b + (size_t)(it + 1) * 256);
        }
        attn_tile(Ks[0], Vs[0], qf, acc, m_, l_, mA, lg, lr, hi, idx0, idx1);
        __syncthreads();
        // ---- tile it+1 (buf 1); prefetch it+2 flies during this compute ----
        if (it + 2 < iters) {
            ISSUE_TILE(it + 2, 0)
            mA = *(const int*)(mbase_b + (size_t)(it + 2) * 256);
        }
        if (it + 1 < iters)
            attn_tile(Ks[1], Vs[1], qf, acc, m_, l_, mB, lg, lr, hi, idx0, idx1);
        __syncthreads();
    }
#undef ISSUE_TILE

    // store unnormalized partials
    const int qrow = b * S_ + q0 + w * 16 + lr;
    float* op = pout + (size_t)(sp * M_ + qrow) * H_ + 4 * lg;
    #pragma unroll
    for (int ni = 0; ni < 8; ++ni)
        *(f32x4*)(op + 16 * ni) = acc[ni];
    if (lg == 0) {
        pm[sp * M_ + qrow] = m_;
        pl[sp * M_ + qrow] = l_;
    }
}

// ---------------------------------------------------------------------------
// Kernel 3: combine KV-split partials and normalize (exp2 domain).
// ---------------------------------------------------------------------------
__global__ __launch_bounds__(256) void combine_kernel(
    const float* __restrict__ pout, const float* __restrict__ pm,
    const float* __restrict__ pl, float* __restrict__ out, const int nsplit)
{
    const int idx = blockIdx.x * 256 + threadIdx.x;
    const int row = idx >> 7;          // global row
    const int h   = idx & (H_ - 1);
    float M = -1e30f;
    for (int sp = 0; sp < nsplit; ++sp) M = fmaxf(M, pm[sp * M_ + row]);
    float Z = 0.f, o = 0.f;
    for (int sp = 0; sp < nsplit; ++sp) {
        const float wgt = exp2f(pm[sp * M_ + row] - M);
        Z += wgt * pl[sp * M_ + row];
        o += wgt * pout[(size_t)(sp * M_ + row) * H_ + h];
    }
    out[idx] = o / Z;
}

// ---------------------------------------------------------------------------
extern "C" void kernel_launch(void* const* d_in, const int* in_sizes, int n_in,
                              void* d_out, int out_size, void* d_ws, size_t ws_size,
                              hipStream_t stream)
{
    (void)in_sizes; (void)n_in; (void)out_size;
    // setup_inputs order: inputs, Wk, bk, Wq, bq, Wv, bv, padding_mask
    const float* x  = (const float*)d_in[0];
    const float* Wk = (const float*)d_in[1];
    const float* bk = (const float*)d_in[2];
    const float* Wq = (const float*)d_in[3];
    const float* bq = (const float*)d_in[4];
    const float* Wv = (const float*)d_in[5];
    const float* bv = (const float*)d_in[6];
    const int* mask = (const int*)d_in[7];

    char* ws = (char*)d_ws;
    const size_t qkvBytes = (size_t)M_ * H_ * sizeof(_Float16);   // 4 MB each
    _Float16* qh = (_Float16*)ws;
    _Float16* kh = (_Float16*)(ws + qkvBytes);
    _Float16* vt = (_Float16*)(ws + 2 * qkvBytes);                // [B][H][S]
    char* rest = ws + 3 * qkvBytes;

    int nsplit = 4;
    const size_t perSplit = (size_t)M_ * H_ * 4 + 2 * (size_t)M_ * 4;
    while (nsplit > 1 && 3 * qkvBytes + (size_t)nsplit * perSplit > ws_size) nsplit >>= 1;

    float* pout = (float*)rest;
    float* pm   = (float*)(rest + (size_t)nsplit * M_ * H_ * 4);
    float* pl   = pm + (size_t)nsplit * M_;

    proj_kernel<<<dim3(M_ / 64, 3), 256, 0, stream>>>(x, Wq, bq, Wk, bk, Wv, bv, qh, kh, vt);
    attn_kernel<<<dim3(256 * nsplit), 256, 0, stream>>>(qh, kh, vt, mask, pout, pm, pl, nsplit);
    combine_kernel<<<dim3(M_ * H_ / 256), 256, 0, stream>>>(pout, pm, pl, (float*)d_out, nsplit);
}

// Round 7
// 112.505 us; speedup vs baseline: 2.3599x; 1.3512x over previous
//
#include <hip/hip_runtime.h>
#include <cmath>

#define B_ 4
#define S_ 4096
#define D_ 1024
#define H_ 128
#define M_ (B_*S_)   // 16384 total rows
#define NQT 32       // S / 128 q-tiles (attn QBLK = 128)

typedef _Float16 half8 __attribute__((ext_vector_type(8)));
typedef _Float16 half4 __attribute__((ext_vector_type(4)));
typedef float f32x4 __attribute__((ext_vector_type(4)));
typedef int i32x4 __attribute__((ext_vector_type(4)));

#define LOG2E 1.44269504088896340f

// async global->LDS, 16B per lane; LDS dest is wave-uniform base + lane*16
__device__ __forceinline__ void gload16(const void* g, void* l) {
    __builtin_amdgcn_global_load_lds(
        (const __attribute__((address_space(1))) unsigned int*)g,
        (__attribute__((address_space(3))) unsigned int*)l,
        16, 0, 0);
}

// ---------------------------------------------------------------------------
// Kernel 0: convert Wq/Wk/Wv (fp32) -> wh fp16 [3][H][D]  (order q,k,v)
// ---------------------------------------------------------------------------
__global__ __launch_bounds__(256) void conv_w(
    const float* __restrict__ Wq, const float* __restrict__ Wk,
    const float* __restrict__ Wv, _Float16* __restrict__ wh)
{
    const int idx  = blockIdx.x * 256 + threadIdx.x;
    const int base = idx * 8;                       // < 3*H*D = 393216
    const int m    = base >> 17;                    // H*D = 131072
    const int off  = base & ((H_ * D_) - 1);
    const float* src = (m == 0 ? Wq : m == 1 ? Wk : Wv) + off;
    const float4 a = ((const float4*)src)[0];
    const float4 c = ((const float4*)src)[1];
    half8 h = { (_Float16)a.x, (_Float16)a.y, (_Float16)a.z, (_Float16)a.w,
                (_Float16)c.x, (_Float16)c.y, (_Float16)c.z, (_Float16)c.w };
    *(half8*)(wh + base) = h;
}

// ---------------------------------------------------------------------------
// Kernel 1: QKV projection.  out = x @ W^T + b  (x fp32, W fp16 via conv_w)
// grid = (M/64, 3): y=0 -> q (scaled by log2e/sqrt(H)), y=1 -> k, y=2 -> v^T
// W staged async via gload16 (XOR-swizzled source, linear LDS dest);
// X reg-staged 2-deep (fp32->fp16 convert). One __syncthreads per K-tile.
// ---------------------------------------------------------------------------
__global__ __launch_bounds__(256, 3) void proj_kernel(
    const float* __restrict__ x, const _Float16* __restrict__ wh,
    const float* __restrict__ bq, const float* __restrict__ bk,
    const float* __restrict__ bv,
    _Float16* __restrict__ qh, _Float16* __restrict__ kh,
    _Float16* __restrict__ vt)
{
    __shared__ _Float16 Xs[2][64][72];     // +8 pad (reg-staged writes)
    __shared__ _Float16 Ws2[2][128][64];   // content at (r,blk)=G[r][blk^(r&7)]

    const int t = threadIdx.x;
    const int yb = blockIdx.y;
    const float* __restrict__ bias = (yb == 0) ? bq : (yb == 1) ? bk : bv;
    const int m0 = blockIdx.x * 64;
    const int w = t >> 6, lane = t & 63;
    const int lg = lane >> 4, lr = lane & 15;

    f32x4 acc[8];
    #pragma unroll
    for (int i = 0; i < 8; ++i) acc[i] = f32x4{0.f, 0.f, 0.f, 0.f};

    const int xrow = t >> 2, xc = (t & 3) * 16;   // X tile: 64x64, 16 f/thread
    const float* xbase = x + (size_t)(m0 + xrow) * D_ + xc;

    // W staging offsets (V-style swizzle): 4 gloads cover rows 32w..32w+32
    int wbyte[4];
    #pragma unroll
    for (int i = 0; i < 4; ++i) {
        const int wrow = 32 * w + 8 * i + (lane >> 3);
        const int wblk = (lane & 7) ^ (lane >> 3);
        wbyte[i] = (wrow * D_ + wblk * 8) * 2;
    }
    const char* whb = (const char*)(wh + (size_t)yb * H_ * D_);

    float4 xfA[4], xfB[4];

#define WISSUE(KT, BUF)                                                       \
    {                                                                         \
        const char* wsrc = whb + (KT) * (64 * 2);                             \
        _Pragma("unroll")                                                     \
        for (int i = 0; i < 4; ++i)                                           \
            gload16(wsrc + wbyte[i], &Ws2[BUF][32 * w + 8 * i][0]);           \
    }
#define XISSUE(KT, XS)                                                        \
    {                                                                         \
        const float4* xs_ = (const float4*)(xbase + (KT) * 64);               \
        _Pragma("unroll") for (int i = 0; i < 4; ++i) XS[i] = xs_[i];         \
    }
#define XWRITE(XS, BUF)                                                       \
    {                                                                         \
        _Pragma("unroll") for (int i = 0; i < 4; ++i) {                       \
            half4 h = { (_Float16)XS[i].x, (_Float16)XS[i].y,                 \
                        (_Float16)XS[i].z, (_Float16)XS[i].w };               \
            *(half4*)&Xs[BUF][xrow][xc + 4 * i] = h;                          \
        }                                                                     \
    }
#define PMFMA(BUF)                                                            \
    {                                                                         \
        _Pragma("unroll") for (int kk = 0; kk < 2; ++kk) {                    \
            half8 a = *(const half8*)&Xs[BUF][w * 16 + lr][kk * 32 + 8 * lg]; \
            _Pragma("unroll") for (int ni = 0; ni < 8; ++ni) {                \
                half8 bfr = *(const half8*)&Ws2[BUF][ni * 16 + lr]            \
                                [((4 * kk + lg) ^ (lr & 7)) * 8];             \
                acc[ni] = __builtin_amdgcn_mfma_f32_16x16x32_f16(a, bfr, acc[ni], 0, 0, 0); \
            }                                                                 \
        }                                                                     \
    }

    WISSUE(0, 0)
    XISSUE(0, xfA)
    XISSUE(1, xfB)
    XWRITE(xfA, 0)
    __syncthreads();   // drains W0 gloads + X0 writes

    for (int kt = 0; kt < 16; kt += 2) {
        // ---- even tile kt (buf 0) ----
        WISSUE(kt + 1, 1)
        if (kt + 2 < 16) XISSUE(kt + 2, xfA)
        PMFMA(0)
        XWRITE(xfB, 1)
        __syncthreads();
        // ---- odd tile kt+1 (buf 1) ----
        if (kt + 2 < 16) WISSUE(kt + 2, 0)
        if (kt + 3 < 16) XISSUE(kt + 3, xfB)
        PMFMA(1)
        if (kt + 2 < 16) XWRITE(xfA, 0)
        __syncthreads();
    }
#undef WISSUE
#undef XISSUE
#undef XWRITE
#undef PMFMA

    // q scale folds 1/sqrt(128) AND log2(e) (softmax runs in exp2 domain)
    const float qscale = 0.08838834764831845f * LOG2E;
    const int rowb = m0 + w * 16 + lg * 4;   // C/D: row = 4*(lane>>4)+r, col = ni*16+lr
    #pragma unroll
    for (int ni = 0; ni < 8; ++ni) {
        const int col = ni * 16 + lr;
        const float bval = bias[col];
        if (yb == 0) {
            #pragma unroll
            for (int r = 0; r < 4; ++r)
                qh[(size_t)(rowb + r) * H_ + col] = (_Float16)((acc[ni][r] + bval) * qscale);
        } else if (yb == 1) {
            #pragma unroll
            for (int r = 0; r < 4; ++r)
                kh[(size_t)(rowb + r) * H_ + col] = (_Float16)(acc[ni][r] + bval);
        } else {
            const int bb = rowb >> 12, s0 = rowb & (S_ - 1);
            half4 h;
            #pragma unroll
            for (int r = 0; r < 4; ++r) h[r] = (_Float16)(acc[ni][r] + bval);
            *(half4*)&vt[(size_t)bb * H_ * S_ + (size_t)col * S_ + s0] = h;
        }
    }
}

// ---------------------------------------------------------------------------
// Kernel 2: flash attention, QBLK=128 (wave owns 32 q-rows = 2x16 sub-blocks).
// K/V fragment reads are shared across the two q-sub-blocks -> LDS bytes per
// unit work halved vs QBLK=64. Swapped-operand MFMA, exp2 softmax, defer-max,
// pre-swizzled-source gload16, ping-pong dbuf, one __syncthreads per tile.
// ---------------------------------------------------------------------------
__device__ __forceinline__ void attn_tile2(
    const _Float16 (&Kb)[64][128], const _Float16 (&Vb)[128][64],
    const half8 (&qf)[2][4], f32x4 (&acc)[2][8], float (&m_)[2], float (&l_)[2],
    int muse, int lg, int lr, bool hi, int idx0, int idx1)
{
    const unsigned long long bz = __ballot(muse == 0);
    // S^T = K Q^T : sf[qs][ni][r] = S'[q-row][kv = 16*ni + 4*lg + r]
    f32x4 sf[2][4];
    #pragma unroll
    for (int qs = 0; qs < 2; ++qs)
        #pragma unroll
        for (int i = 0; i < 4; ++i) sf[qs][i] = f32x4{0.f, 0.f, 0.f, 0.f};
    #pragma unroll
    for (int kk = 0; kk < 4; ++kk) {
        #pragma unroll
        for (int ni = 0; ni < 4; ++ni) {
            half8 kb = *(const half8*)&Kb[ni * 16 + lr][((4 * kk + lg) ^ (lr & 7)) * 8];
            #pragma unroll
            for (int qs = 0; qs < 2; ++qs)
                sf[qs][ni] = __builtin_amdgcn_mfma_f32_16x16x32_f16(kb, qf[qs][kk], sf[qs][ni], 0, 0, 0);
        }
    }

    i32x4 pbi[2][2];
    #pragma unroll
    for (int qs = 0; qs < 2; ++qs) {
        if (bz) {   // padding mask (reference: where(mask==0, -1e9))
            #pragma unroll
            for (int ni = 0; ni < 4; ++ni) {
                #pragma unroll
                for (int r = 0; r < 4; ++r)
                    if ((bz >> (16 * ni + 4 * lg + r)) & 1ull) sf[qs][ni][r] = -3e9f;
            }
        }
        // online softmax in exp2 domain (lane-local except 2 shuffles)
        float tmax = fmaxf(
            fmaxf(fmaxf(fmaxf(sf[qs][0][0], sf[qs][0][1]), fmaxf(sf[qs][0][2], sf[qs][0][3])),
                  fmaxf(fmaxf(sf[qs][1][0], sf[qs][1][1]), fmaxf(sf[qs][1][2], sf[qs][1][3]))),
            fmaxf(fmaxf(fmaxf(sf[qs][2][0], sf[qs][2][1]), fmaxf(sf[qs][2][2], sf[qs][2][3])),
                  fmaxf(fmaxf(sf[qs][3][0], sf[qs][3][1]), fmaxf(sf[qs][3][2], sf[qs][3][3]))));
        tmax = fmaxf(tmax, __shfl_xor(tmax, 16));
        tmax = fmaxf(tmax, __shfl_xor(tmax, 32));
        if (!__all(tmax <= m_[qs] + 8.f)) {   // defer-max
            const float mn  = fmaxf(m_[qs], tmax);
            const float scl = exp2f(m_[qs] - mn);
            m_[qs] = mn; l_[qs] *= scl;
            #pragma unroll
            for (int ni = 0; ni < 8; ++ni) acc[qs][ni] *= scl;
        }
        float rsum = 0.f;
        #pragma unroll
        for (int ni = 0; ni < 4; ++ni) {
            #pragma unroll
            for (int r = 0; r < 4; ++r) {
                const float p = exp2f(sf[qs][ni][r] - m_[qs]);
                sf[qs][ni][r] = p;
                rsum += p;
            }
        }
        rsum += __shfl_xor(rsum, 16);
        rsum += __shfl_xor(rsum, 32);
        l_[qs] += rsum;

        // pack P to fp16 pairs, exchange to PV B-fragment layout via bpermute
        int pk[4][2];
        #pragma unroll
        for (int ni = 0; ni < 4; ++ni) {
            #pragma unroll
            for (int rp = 0; rp < 2; ++rp) {
                auto h2 = __builtin_amdgcn_cvt_pkrtz(sf[qs][ni][2 * rp], sf[qs][ni][2 * rp + 1]);
                pk[ni][rp] = __builtin_bit_cast(int, h2);
            }
        }
        #pragma unroll
        for (int kk = 0; kk < 2; ++kk) {
            #pragma unroll
            for (int dd = 0; dd < 4; ++dd) {
                const int sidx = (dd >> 1) ? idx1 : idx0;
                const int a  = __builtin_amdgcn_ds_bpermute(sidx, pk[2 * kk][dd & 1]);
                const int bb = __builtin_amdgcn_ds_bpermute(sidx, pk[2 * kk + 1][dd & 1]);
                pbi[qs][kk][dd] = hi ? bb : a;
            }
        }
    }
    // O^T += V^T P^T  (V fragment shared across q-sub-blocks)
    #pragma unroll
    for (int kk = 0; kk < 2; ++kk) {
        #pragma unroll
        for (int ni = 0; ni < 8; ++ni) {
            half8 vb = *(const half8*)&Vb[ni * 16 + lr][((4 * kk + lg) ^ (lr & 7)) * 8];
            #pragma unroll
            for (int qs = 0; qs < 2; ++qs) {
                const half8 pb = __builtin_bit_cast(half8, pbi[qs][kk]);
                acc[qs][ni] = __builtin_amdgcn_mfma_f32_16x16x32_f16(vb, pb, acc[qs][ni], 0, 0, 0);
            }
        }
    }
}

__global__ __launch_bounds__(256, 2) void attn_kernel(
    const _Float16* __restrict__ qh, const _Float16* __restrict__ kh,
    const _Float16* __restrict__ vt, const int* __restrict__ mask,
    float* __restrict__ pout, float* __restrict__ pm, float* __restrict__ pl,
    const int nsplit)
{
    __shared__ _Float16 Ks[2][64][128];   // [buf][kv][d]; content swizzled
    __shared__ _Float16 Vs[2][128][64];   // [buf][h][kv]

    const int t = threadIdx.x;
    const int id = blockIdx.x;
    // L2-locality swizzle: each XCD owns ncombo/8 (b,split) combos.
    int qt, sp, b;
    const int ncombo = B_ * nsplit;
    if ((ncombo & 7) == 0) {
        const int per_xcd = ncombo >> 3;
        const int j = id >> 3;
        qt = j & (NQT - 1);
        const int combo = (id & 7) * per_xcd + (j >> 5);   // log2(NQT)=5
        sp = combo % nsplit; b = combo / nsplit;
    } else {
        qt = id & (NQT - 1);
        const int rest = id >> 5;
        sp = rest % nsplit; b = rest / nsplit;
    }
    const int q0 = qt * 128;
    const int w = t >> 6, lane = t & 63;
    const int lg = lane >> 4, lr = lane & 15;
    const int kvlen  = S_ / nsplit;
    const int iters  = kvlen >> 6;
    const int kvbase = sp * kvlen;

    // per-lane byte offsets of the SWIZZLED global source (loop-invariant)
    int kbyte[4], vbyte[4];
    #pragma unroll
    for (int i = 0; i < 4; ++i) {
        const int krow = 16 * w + 4 * i + (lane >> 4);
        const int kblk = (lane & 15) ^ (krow & 7);
        kbyte[i] = (krow * H_ + kblk * 8) * 2;
        const int vrow = 32 * w + 8 * i + (lane >> 3);
        const int vblk = (lane & 7) ^ (lane >> 3);   // vrow&7 == lane>>3
        vbyte[i] = (vrow * S_ + vblk * 8) * 2;
    }
    const char* kbase_b = (const char*)(kh + (size_t)(b * S_ + kvbase) * H_);
    const char* vbase_b = (const char*)(vt + (size_t)b * H_ * S_ + kvbase);
    const char* mbase_b = (const char*)(mask + b * S_ + kvbase + lane);

#define ISSUE_TILE(IT, NB)                                                    \
    {                                                                         \
        const char* kb_t = kbase_b + (size_t)(IT) * (64 * H_ * 2);            \
        const char* vb_t = vbase_b + (size_t)(IT) * (64 * 2);                 \
        _Pragma("unroll")                                                     \
        for (int i = 0; i < 4; ++i)                                           \
            gload16(kb_t + kbyte[i], &Ks[NB][16 * w + 4 * i][0]);             \
        _Pragma("unroll")                                                     \
        for (int i = 0; i < 4; ++i)                                           \
            gload16(vb_t + vbyte[i], &Vs[NB][32 * w + 8 * i][0]);             \
    }

    // Q fragments: Q[q = q0 + w*32 + qs*16 + lr][d = kk*32 + 8*lg + j]
    half8 qf[2][4];
    #pragma unroll
    for (int qs = 0; qs < 2; ++qs) {
        const _Float16* qp = qh + (size_t)(b * S_ + q0 + w * 32 + qs * 16 + lr) * H_ + 8 * lg;
        #pragma unroll
        for (int kk = 0; kk < 4; ++kk) qf[qs][kk] = *(const half8*)(qp + kk * 32);
    }

    float m_[2] = { -1e30f, -1e30f }, l_[2] = { 0.f, 0.f };
    f32x4 acc[2][8];   // O^T: acc[qs][ni][r] = O[q-row][h = 16*ni + 4*lg + r]
    #pragma unroll
    for (int qs = 0; qs < 2; ++qs)
        #pragma unroll
        for (int i = 0; i < 8; ++i) acc[qs][i] = f32x4{0.f, 0.f, 0.f, 0.f};

    const bool hi = (lg >= 2);
    const int idx0 = (16 * ((2 * lg + 0) & 3) + lr) * 4;  // bpermute src (bytes)
    const int idx1 = (16 * ((2 * lg + 1) & 3) + lr) * 4;

    ISSUE_TILE(0, 0)
    int mA = *(const int*)mbase_b;
    int mB = 0;
    __syncthreads();   // tile 0 staged

    for (int it = 0; it < iters; it += 2) {
        // ---- tile it (buf 0); prefetch it+1 flies during this compute ----
        if (it + 1 < iters) {
            ISSUE_TILE(it + 1, 1)
            mB = *(const int*)(mbase_b + (size_t)(it + 1) * 256);
        }
        attn_tile2(Ks[0], Vs[0], qf, acc, m_, l_, mA, lg, lr, hi, idx0, idx1);
        __syncthreads();
        // ---- tile it+1 (buf 1); prefetch it+2 flies during this compute ----
        if (it + 2 < iters) {
            ISSUE_TILE(it + 2, 0)
            mA = *(const int*)(mbase_b + (size_t)(it + 2) * 256);
        }
        if (it + 1 < iters)
            attn_tile2(Ks[1], Vs[1], qf, acc, m_, l_, mB, lg, lr, hi, idx0, idx1);
        __syncthreads();
    }
#undef ISSUE_TILE

    // store unnormalized partials
    #pragma unroll
    for (int qs = 0; qs < 2; ++qs) {
        const int qrow = b * S_ + q0 + w * 32 + qs * 16 + lr;
        float* op = pout + (size_t)(sp * M_ + qrow) * H_ + 4 * lg;
        #pragma unroll
        for (int ni = 0; ni < 8; ++ni)
            *(f32x4*)(op + 16 * ni) = acc[qs][ni];
        if (lg == 0) {
            pm[sp * M_ + qrow] = m_[qs];
            pl[sp * M_ + qrow] = l_[qs];
        }
    }
}

// ---------------------------------------------------------------------------
// Kernel 3: combine KV-split partials and normalize (exp2 domain).
// ---------------------------------------------------------------------------
__global__ __launch_bounds__(256) void combine_kernel(
    const float* __restrict__ pout, const float* __restrict__ pm,
    const float* __restrict__ pl, float* __restrict__ out, const int nsplit)
{
    const int idx = blockIdx.x * 256 + threadIdx.x;
    const int row = idx >> 7;          // global row
    const int h   = idx & (H_ - 1);
    float M = -1e30f;
    for (int sp = 0; sp < nsplit; ++sp) M = fmaxf(M, pm[sp * M_ + row]);
    float Z = 0.f, o = 0.f;
    for (int sp = 0; sp < nsplit; ++sp) {
        const float wgt = exp2f(pm[sp * M_ + row] - M);
        Z += wgt * pl[sp * M_ + row];
        o += wgt * pout[(size_t)(sp * M_ + row) * H_ + h];
    }
    out[idx] = o / Z;
}

// ---------------------------------------------------------------------------
extern "C" void kernel_launch(void* const* d_in, const int* in_sizes, int n_in,
                              void* d_out, int out_size, void* d_ws, size_t ws_size,
                              hipStream_t stream)
{
    (void)in_sizes; (void)n_in; (void)out_size;
    // setup_inputs order: inputs, Wk, bk, Wq, bq, Wv, bv, padding_mask
    const float* x  = (const float*)d_in[0];
    const float* Wk = (const float*)d_in[1];
    const float* bk = (const float*)d_in[2];
    const float* Wq = (const float*)d_in[3];
    const float* bq = (const float*)d_in[4];
    const float* Wv = (const float*)d_in[5];
    const float* bv = (const float*)d_in[6];
    const int* mask = (const int*)d_in[7];

    char* ws = (char*)d_ws;
    const size_t qkvBytes = (size_t)M_ * H_ * sizeof(_Float16);   // 4 MB each
    _Float16* qh = (_Float16*)ws;
    _Float16* kh = (_Float16*)(ws + qkvBytes);
    _Float16* vt = (_Float16*)(ws + 2 * qkvBytes);                // [B][H][S]
    _Float16* wh = (_Float16*)(ws + 3 * qkvBytes);                // [3][H][D]
    const size_t whBytes = (size_t)3 * H_ * D_ * sizeof(_Float16);
    char* rest = ws + 3 * qkvBytes + whBytes;

    int nsplit = 4;
    const size_t perSplit = (size_t)M_ * H_ * 4 + 2 * (size_t)M_ * 4;
    while (nsplit > 1 &&
           3 * qkvBytes + whBytes + (size_t)nsplit * perSplit > ws_size) nsplit >>= 1;

    float* pout = (float*)rest;
    float* pm   = (float*)(rest + (size_t)nsplit * M_ * H_ * 4);
    float* pl   = pm + (size_t)nsplit * M_;

    conv_w<<<dim3(3 * H_ * D_ / (256 * 8)), 256, 0, stream>>>(Wq, Wk, Wv, wh);
    proj_kernel<<<dim3(M_ / 64, 3), 256, 0, stream>>>(x, wh, bq, bk, bv, qh, kh, vt);
    attn_kernel<<<dim3(NQT * B_ * nsplit), 256, 0, stream>>>(qh, kh, vt, mask, pout, pm, pl, nsplit);
    combine_kernel<<<dim3(M_ * H_ / 256), 256, 0, stream>>>(pout, pm, pl, (float*)d_out, nsplit);
}

// Round 9
// 109.894 us; speedup vs baseline: 2.4160x; 1.0238x over previous
//
#include <hip/hip_runtime.h>
#include <cmath>

#define B_ 4
#define S_ 4096
#define D_ 1024
#define H_ 128
#define M_ (B_*S_)   // 16384 total rows
#define NQT 32       // S / 128 q-tiles (attn QBLK = 128)

typedef _Float16 half8 __attribute__((ext_vector_type(8)));
typedef _Float16 half4 __attribute__((ext_vector_type(4)));
typedef float f32x4 __attribute__((ext_vector_type(4)));
typedef float f32x16 __attribute__((ext_vector_type(16)));
typedef int i32x4 __attribute__((ext_vector_type(4)));

#define LOG2E 1.44269504088896340f

// async global->LDS, 16B per lane; LDS dest is wave-uniform base + lane*16
__device__ __forceinline__ void gload16(const void* g, void* l) {
    __builtin_amdgcn_global_load_lds(
        (const __attribute__((address_space(1))) unsigned int*)g,
        (__attribute__((address_space(3))) unsigned int*)l,
        16, 0, 0);
}

// ---------------------------------------------------------------------------
// Kernel 0: convert Wq/Wk/Wv (fp32) -> wh fp16 [3][H][D]  (order q,k,v)
// ---------------------------------------------------------------------------
__global__ __launch_bounds__(256) void conv_w(
    const float* __restrict__ Wq, const float* __restrict__ Wk,
    const float* __restrict__ Wv, _Float16* __restrict__ wh)
{
    const int idx  = blockIdx.x * 256 + threadIdx.x;
    const int base = idx * 8;                       // < 3*H*D = 393216
    const int m    = base >> 17;                    // H*D = 131072
    const int off  = base & ((H_ * D_) - 1);
    const float* src = (m == 0 ? Wq : m == 1 ? Wk : Wv) + off;
    const float4 a = ((const float4*)src)[0];
    const float4 c = ((const float4*)src)[1];
    half8 h = { (_Float16)a.x, (_Float16)a.y, (_Float16)a.z, (_Float16)a.w,
                (_Float16)c.x, (_Float16)c.y, (_Float16)c.z, (_Float16)c.w };
    *(half8*)(wh + base) = h;
}

// ---------------------------------------------------------------------------
// Kernel 1: QKV projection.  out = x @ W^T + b  (x fp32, W fp16 via conv_w)
// grid = (M/64, 3): y=0 -> q (scaled by log2e/sqrt(H)), y=1 -> k, y=2 -> v^T
// ---------------------------------------------------------------------------
__global__ __launch_bounds__(256, 3) void proj_kernel(
    const float* __restrict__ x, const _Float16* __restrict__ wh,
    const float* __restrict__ bq, const float* __restrict__ bk,
    const float* __restrict__ bv,
    _Float16* __restrict__ qh, _Float16* __restrict__ kh,
    _Float16* __restrict__ vt)
{
    __shared__ _Float16 Xs[2][64][72];     // +8 pad (reg-staged writes)
    __shared__ _Float16 Ws2[2][128][64];   // content at (r,blk)=G[r][blk^(r&7)]

    const int t = threadIdx.x;
    const int yb = blockIdx.y;
    const float* __restrict__ bias = (yb == 0) ? bq : (yb == 1) ? bk : bv;
    const int m0 = blockIdx.x * 64;
    const int w = t >> 6, lane = t & 63;
    const int lg = lane >> 4, lr = lane & 15;

    f32x4 acc[8];
    #pragma unroll
    for (int i = 0; i < 8; ++i) acc[i] = f32x4{0.f, 0.f, 0.f, 0.f};

    const int xrow = t >> 2, xc = (t & 3) * 16;   // X tile: 64x64, 16 f/thread
    const float* xbase = x + (size_t)(m0 + xrow) * D_ + xc;

    // W staging offsets (V-style swizzle): 4 gloads cover rows 32w..32w+32
    int wbyte[4];
    #pragma unroll
    for (int i = 0; i < 4; ++i) {
        const int wrow = 32 * w + 8 * i + (lane >> 3);
        const int wblk = (lane & 7) ^ (lane >> 3);
        wbyte[i] = (wrow * D_ + wblk * 8) * 2;
    }
    const char* whb = (const char*)(wh + (size_t)yb * H_ * D_);

    float4 xfA[4], xfB[4];

#define WISSUE(KT, BUF)                                                       \
    {                                                                         \
        const char* wsrc = whb + (KT) * (64 * 2);                             \
        _Pragma("unroll")                                                     \
        for (int i = 0; i < 4; ++i)                                           \
            gload16(wsrc + wbyte[i], &Ws2[BUF][32 * w + 8 * i][0]);           \
    }
#define XISSUE(KT, XS)                                                        \
    {                                                                         \
        const float4* xs_ = (const float4*)(xbase + (KT) * 64);               \
        _Pragma("unroll") for (int i = 0; i < 4; ++i) XS[i] = xs_[i];         \
    }
#define XWRITE(XS, BUF)                                                       \
    {                                                                         \
        _Pragma("unroll") for (int i = 0; i < 4; ++i) {                       \
            half4 h = { (_Float16)XS[i].x, (_Float16)XS[i].y,                 \
                        (_Float16)XS[i].z, (_Float16)XS[i].w };               \
            *(half4*)&Xs[BUF][xrow][xc + 4 * i] = h;                          \
        }                                                                     \
    }
#define PMFMA(BUF)                                                            \
    {                                                                         \
        _Pragma("unroll") for (int kk = 0; kk < 2; ++kk) {                    \
            half8 a = *(const half8*)&Xs[BUF][w * 16 + lr][kk * 32 + 8 * lg]; \
            _Pragma("unroll") for (int ni = 0; ni < 8; ++ni) {                \
                half8 bfr = *(const half8*)&Ws2[BUF][ni * 16 + lr]            \
                                [((4 * kk + lg) ^ (lr & 7)) * 8];             \
                acc[ni] = __builtin_amdgcn_mfma_f32_16x16x32_f16(a, bfr, acc[ni], 0, 0, 0); \
            }                                                                 \
        }                                                                     \
    }

    WISSUE(0, 0)
    XISSUE(0, xfA)
    XISSUE(1, xfB)
    XWRITE(xfA, 0)
    __syncthreads();   // drains W0 gloads + X0 writes

    for (int kt = 0; kt < 16; kt += 2) {
        // ---- even tile kt (buf 0) ----
        WISSUE(kt + 1, 1)
        if (kt + 2 < 16) XISSUE(kt + 2, xfA)
        PMFMA(0)
        XWRITE(xfB, 1)
        __syncthreads();
        // ---- odd tile kt+1 (buf 1) ----
        if (kt + 2 < 16) WISSUE(kt + 2, 0)
        if (kt + 3 < 16) XISSUE(kt + 3, xfB)
        PMFMA(1)
        if (kt + 2 < 16) XWRITE(xfA, 0)
        __syncthreads();
    }
#undef WISSUE
#undef XISSUE
#undef XWRITE
#undef PMFMA

    // q scale folds 1/sqrt(128) AND log2(e) (softmax runs in exp2 domain)
    const float qscale = 0.08838834764831845f * LOG2E;
    const int rowb = m0 + w * 16 + lg * 4;   // C/D: row = 4*(lane>>4)+r, col = ni*16+lr
    #pragma unroll
    for (int ni = 0; ni < 8; ++ni) {
        const int col = ni * 16 + lr;
        const float bval = bias[col];
        if (yb == 0) {
            #pragma unroll
            for (int r = 0; r < 4; ++r)
                qh[(size_t)(rowb + r) * H_ + col] = (_Float16)((acc[ni][r] + bval) * qscale);
        } else if (yb == 1) {
            #pragma unroll
            for (int r = 0; r < 4; ++r)
                kh[(size_t)(rowb + r) * H_ + col] = (_Float16)(acc[ni][r] + bval);
        } else {
            const int bb = rowb >> 12, s0 = rowb & (S_ - 1);
            half4 h;
            #pragma unroll
            for (int r = 0; r < 4; ++r) h[r] = (_Float16)(acc[ni][r] + bval);
            *(half4*)&vt[(size_t)bb * H_ * S_ + (size_t)col * S_ + s0] = h;
        }
    }
}

// ---------------------------------------------------------------------------
// Kernel 2: flash attention, 32x32x16 MFMA core.
// Swapped operands: S^T = mfma(K, Q^T) -> lane owns ONE q-row (q = lane&31);
// softmax: in-lane fmax over 32 + one shfl_xor(32). P exchange to the PV
// B-fragment via __shfl_xor(32) (direction-unambiguous; 8 shfls/tile).
// C/D map (m74/m101): col = lane&31, row = (r&3) + 8*(r>>2) + 4*(lane>>5).
// A/B map: row/col = lane&31, k = 8*(lane>>5) + j.
// ---------------------------------------------------------------------------
__device__ __forceinline__ void attn_tile32(
    const _Float16 (&Kb)[64][128], const _Float16 (&Vb)[128][64],
    const half8 (&qf)[8], f32x16 (&acc2)[4], float& m_, float& l_,
    int muse, int lane)
{
    const unsigned long long bz = __ballot(muse == 0);
    const int l31 = lane & 31, l7 = lane & 7, hi = lane >> 5;

    // S^T = K Q^T : sf[nb][r] = S'[kv = 32nb + (r&3)+8*(r>>2)+4hi][q = l31]
    f32x16 sf[2];
    #pragma unroll
    for (int nb = 0; nb < 2; ++nb)
        #pragma unroll
        for (int r = 0; r < 16; ++r) sf[nb][r] = 0.f;
    #pragma unroll
    for (int kt = 0; kt < 8; ++kt) {
        #pragma unroll
        for (int nb = 0; nb < 2; ++nb) {
            half8 kb = *(const half8*)&Kb[nb * 32 + l31][((2 * kt + hi) ^ l7) * 8];
            sf[nb] = __builtin_amdgcn_mfma_f32_32x32x16_f16(kb, qf[kt], sf[nb], 0, 0, 0);
        }
    }
    if (bz) {   // padding mask (reference: where(mask==0, -1e9))
        #pragma unroll
        for (int nb = 0; nb < 2; ++nb)
            #pragma unroll
            for (int r = 0; r < 16; ++r) {
                const int kv = nb * 32 + (r & 3) + 8 * (r >> 2) + 4 * hi;
                if ((bz >> kv) & 1ull) sf[nb][r] = -3e9f;
            }
    }
    // online softmax in exp2 domain: one q-row per lane, ONE shuffle
    float tmax = sf[0][0];
    #pragma unroll
    for (int nb = 0; nb < 2; ++nb)
        #pragma unroll
        for (int r = 0; r < 16; ++r) tmax = fmaxf(tmax, sf[nb][r]);
    tmax = fmaxf(tmax, __shfl_xor(tmax, 32));
    if (!__all(tmax <= m_ + 8.f)) {   // defer-max: skip rescale when safe
        const float mn  = fmaxf(m_, tmax);
        const float scl = exp2f(m_ - mn);
        m_ = mn; l_ *= scl;
        #pragma unroll
        for (int hb = 0; hb < 4; ++hb) acc2[hb] *= scl;
    }
    float rsum = 0.f;
    #pragma unroll
    for (int nb = 0; nb < 2; ++nb)
        #pragma unroll
        for (int r = 0; r < 16; ++r) {
            const float p = exp2f(sf[nb][r] - m_);
            sf[nb][r] = p;
            rsum += p;
        }
    rsum += __shfl_xor(rsum, 32);
    l_ += rsum;

    // pack P pairs: pkw[nb][i] holds kv = 32nb + 8*(i>>1) + 4hi + 2*(i&1), +1
    int pkw[2][8];
    #pragma unroll
    for (int nb = 0; nb < 2; ++nb)
        #pragma unroll
        for (int i = 0; i < 8; ++i) {
            auto h2 = __builtin_amdgcn_cvt_pkrtz(sf[nb][2 * i], sf[nb][2 * i + 1]);
            pkw[nb][i] = __builtin_bit_cast(int, h2);
        }
    // exchange across lane halves: word n of chunk (nb,hf) on half hi must
    // hold kv = 32nb + 16hf + 8hi + 2n  ->  owner half hi'=n>>1... derived:
    // lo lanes keep w0,w1 and receive other-half's w0,w1 as w2,w3;
    // hi lanes keep w2,w3 and receive other-half's w2,w3 as w0,w1.
    #pragma unroll
    for (int nb = 0; nb < 2; ++nb)
        #pragma unroll
        for (int hf = 0; hf < 2; ++hf) {
            const int i0 = hf * 4;
            const int sA = hi ? pkw[nb][i0 + 0] : pkw[nb][i0 + 2];
            const int sB = hi ? pkw[nb][i0 + 1] : pkw[nb][i0 + 3];
            const int rA = __shfl_xor(sA, 32);   // lo<-hi's w0 ; hi<-lo's w2
            const int rB = __shfl_xor(sB, 32);   // lo<-hi's w1 ; hi<-lo's w3
            const int n0 = hi ? rA : pkw[nb][i0 + 0];
            const int n1 = hi ? rB : pkw[nb][i0 + 1];
            const int n2 = hi ? pkw[nb][i0 + 2] : rA;
            const int n3 = hi ? pkw[nb][i0 + 3] : rB;
            pkw[nb][i0 + 0] = n0; pkw[nb][i0 + 1] = n1;
            pkw[nb][i0 + 2] = n2; pkw[nb][i0 + 3] = n3;
        }
    // O^T += V^T P^T : acc2[hb][r] = O[q=l31][h = 32hb + (r&3)+8*(r>>2)+4hi]
    #pragma unroll
    for (int s = 0; s < 4; ++s) {
        const int nb = s >> 1, hf = s & 1;
        const half8 pb = __builtin_bit_cast(half8,
            i32x4{ pkw[nb][hf * 4 + 0], pkw[nb][hf * 4 + 1],
                   pkw[nb][hf * 4 + 2], pkw[nb][hf * 4 + 3] });
        #pragma unroll
        for (int hb = 0; hb < 4; ++hb) {
            half8 vb = *(const half8*)&Vb[hb * 32 + l31][((2 * s + hi) ^ l7) * 8];
            acc2[hb] = __builtin_amdgcn_mfma_f32_32x32x16_f16(vb, pb, acc2[hb], 0, 0, 0);
        }
    }
}

__global__ __launch_bounds__(256, 2) void attn_kernel(
    const _Float16* __restrict__ qh, const _Float16* __restrict__ kh,
    const _Float16* __restrict__ vt, const int* __restrict__ mask,
    float* __restrict__ pout, float* __restrict__ pm, float* __restrict__ pl,
    const int nsplit)
{
    __shared__ _Float16 Ks[2][64][128];   // [buf][kv][d]; content swizzled
    __shared__ _Float16 Vs[2][128][64];   // [buf][h][kv]

    const int t = threadIdx.x;
    const int id = blockIdx.x;
    // L2-locality swizzle: each XCD owns ncombo/8 (b,split) combos.
    int qt, sp, b;
    const int ncombo = B_ * nsplit;
    if ((ncombo & 7) == 0) {
        const int per_xcd = ncombo >> 3;
        const int j = id >> 3;
        qt = j & (NQT - 1);
        const int combo = (id & 7) * per_xcd + (j >> 5);   // log2(NQT)=5
        sp = combo % nsplit; b = combo / nsplit;
    } else {
        qt = id & (NQT - 1);
        const int rest = id >> 5;
        sp = rest % nsplit; b = rest / nsplit;
    }
    const int q0 = qt * 128;
    const int w = t >> 6, lane = t & 63;
    const int l31 = lane & 31, hi = lane >> 5;
    const int kvlen  = S_ / nsplit;
    const int iters  = kvlen >> 6;
    const int kvbase = sp * kvlen;

    // per-lane byte offsets of the SWIZZLED global source (loop-invariant)
    int kbyte[4], vbyte[4];
    #pragma unroll
    for (int i = 0; i < 4; ++i) {
        const int krow = 16 * w + 4 * i + (lane >> 4);
        const int kblk = (lane & 15) ^ (krow & 7);
        kbyte[i] = (krow * H_ + kblk * 8) * 2;
        const int vrow = 32 * w + 8 * i + (lane >> 3);
        const int vblk = (lane & 7) ^ (lane >> 3);   // vrow&7 == lane>>3
        vbyte[i] = (vrow * S_ + vblk * 8) * 2;
    }
    const char* kbase_b = (const char*)(kh + (size_t)(b * S_ + kvbase) * H_);
    const char* vbase_b = (const char*)(vt + (size_t)b * H_ * S_ + kvbase);
    const char* mbase_b = (const char*)(mask + b * S_ + kvbase + lane);

#define ISSUE_TILE(IT, NB)                                                    \
    {                                                                         \
        const char* kb_t = kbase_b + (size_t)(IT) * (64 * H_ * 2);            \
        const char* vb_t = vbase_b + (size_t)(IT) * (64 * 2);                 \
        _Pragma("unroll")                                                     \
        for (int i = 0; i < 4; ++i)                                           \
            gload16(kb_t + kbyte[i], &Ks[NB][16 * w + 4 * i][0]);             \
        _Pragma("unroll")                                                     \
        for (int i = 0; i < 4; ++i)                                           \
            gload16(vb_t + vbyte[i], &Vs[NB][32 * w + 8 * i][0]);             \
    }

    // Q fragments: lane owns q-row (q0 + 32w + l31); d = 16kt + 8hi + j
    half8 qf[8];
    {
        const _Float16* qp = qh + (size_t)(b * S_ + q0 + 32 * w + l31) * H_ + 8 * hi;
        #pragma unroll
        for (int kt = 0; kt < 8; ++kt) qf[kt] = *(const half8*)(qp + 16 * kt);
    }

    float m_ = -1e30f, l_ = 0.f;
    f32x16 acc2[4];
    #pragma unroll
    for (int hb = 0; hb < 4; ++hb)
        #pragma unroll
        for (int r = 0; r < 16; ++r) acc2[hb][r] = 0.f;

    ISSUE_TILE(0, 0)
    int mA = *(const int*)mbase_b;
    int mB = 0;
    __syncthreads();   // tile 0 staged

    for (int it = 0; it < iters; it += 2) {
        // ---- tile it (buf 0); prefetch it+1 flies during this compute ----
        if (it + 1 < iters) {
            ISSUE_TILE(it + 1, 1)
            mB = *(const int*)(mbase_b + (size_t)(it + 1) * 256);
        }
        attn_tile32(Ks[0], Vs[0], qf, acc2, m_, l_, mA, lane);
        __syncthreads();
        // ---- tile it+1 (buf 1); prefetch it+2 flies during this compute ----
        if (it + 2 < iters) {
            ISSUE_TILE(it + 2, 0)
            mA = *(const int*)(mbase_b + (size_t)(it + 2) * 256);
        }
        if (it + 1 < iters)
            attn_tile32(Ks[1], Vs[1], qf, acc2, m_, l_, mB, lane);
        __syncthreads();
    }
#undef ISSUE_TILE

    // store unnormalized partials: lane writes its q-row, 64 h-values
    const int qrow = b * S_ + q0 + 32 * w + l31;
    float* op = pout + (size_t)(sp * M_ + qrow) * H_;
    #pragma unroll
    for (int hb = 0; hb < 4; ++hb)
        #pragma unroll
        for (int i = 0; i < 8; ++i) {
            const int h = hb * 32 + 2 * (i & 1) + 8 * (i >> 1) + 4 * hi;
            float2 v2 = make_float2(acc2[hb][2 * i], acc2[hb][2 * i + 1]);
            *(float2*)(op + h) = v2;
        }
    if (hi == 0) {
        pm[sp * M_ + qrow] = m_;
        pl[sp * M_ + qrow] = l_;
    }
}

// ---------------------------------------------------------------------------
// Kernel 3: combine KV-split partials and normalize (exp2 domain).
// ---------------------------------------------------------------------------
__global__ __launch_bounds__(256) void combine_kernel(
    const float* __restrict__ pout, const float* __restrict__ pm,
    const float* __restrict__ pl, float* __restrict__ out, const int nsplit)
{
    const int idx = blockIdx.x * 256 + threadIdx.x;
    const int row = idx >> 7;          // global row
    const int h   = idx & (H_ - 1);
    float M = -1e30f;
    for (int sp = 0; sp < nsplit; ++sp) M = fmaxf(M, pm[sp * M_ + row]);
    float Z = 0.f, o = 0.f;
    for (int sp = 0; sp < nsplit; ++sp) {
        const float wgt = exp2f(pm[sp * M_ + row] - M);
        Z += wgt * pl[sp * M_ + row];
        o += wgt * pout[(size_t)(sp * M_ + row) * H_ + h];
    }
    out[idx] = o / Z;
}

// ---------------------------------------------------------------------------
extern "C" void kernel_launch(void* const* d_in, const int* in_sizes, int n_in,
                              void* d_out, int out_size, void* d_ws, size_t ws_size,
                              hipStream_t stream)
{
    (void)in_sizes; (void)n_in; (void)out_size;
    // setup_inputs order: inputs, Wk, bk, Wq, bq, Wv, bv, padding_mask
    const float* x  = (const float*)d_in[0];
    const float* Wk = (const float*)d_in[1];
    const float* bk = (const float*)d_in[2];
    const float* Wq = (const float*)d_in[3];
    const float* bq = (const float*)d_in[4];
    const float* Wv = (const float*)d_in[5];
    const float* bv = (const float*)d_in[6];
    const int* mask = (const int*)d_in[7];

    char* ws = (char*)d_ws;
    const size_t qkvBytes = (size_t)M_ * H_ * sizeof(_Float16);   // 4 MB each
    _Float16* qh = (_Float16*)ws;
    _Float16* kh = (_Float16*)(ws + qkvBytes);
    _Float16* vt = (_Float16*)(ws + 2 * qkvBytes);                // [B][H][S]
    _Float16* wh = (_Float16*)(ws + 3 * qkvBytes);                // [3][H][D]
    const size_t whBytes = (size_t)3 * H_ * D_ * sizeof(_Float16);
    char* rest = ws + 3 * qkvBytes + whBytes;

    int nsplit = 4;
    const size_t perSplit = (size_t)M_ * H_ * 4 + 2 * (size_t)M_ * 4;
    while (nsplit > 1 &&
           3 * qkvBytes + whBytes + (size_t)nsplit * perSplit > ws_size) nsplit >>= 1;

    float* pout = (float*)rest;
    float* pm   = (float*)(rest + (size_t)nsplit * M_ * H_ * 4);
    float* pl   = pm + (size_t)nsplit * M_;

    conv_w<<<dim3(3 * H_ * D_ / (256 * 8)), 256, 0, stream>>>(Wq, Wk, Wv, wh);
    proj_kernel<<<dim3(M_ / 64, 3), 256, 0, stream>>>(x, wh, bq, bk, bv, qh, kh, vt);
    attn_kernel<<<dim3(NQT * B_ * nsplit), 256, 0, stream>>>(qh, kh, vt, mask, pout, pm, pl, nsplit);
    combine_kernel<<<dim3(M_ * H_ / 256), 256, 0, stream>>>(pout, pm, pl, (float*)d_out, nsplit);
}